// Round 9
// baseline (534.685 us; speedup 1.0000x reference)
//
#include <hip/hip_runtime.h>
#include <math.h>

typedef unsigned short u16;
typedef __attribute__((ext_vector_type(8))) short short8;
typedef __attribute__((ext_vector_type(4))) float f32x4;

#define BB 32
#define WW 256
#define DD 512
#define NHEADS 4
#define NHID 128

__device__ __forceinline__ u16 f2bf(float f) {
  union { float f; unsigned int i; } x; x.f = f;
  unsigned int i = x.i;
  i += 0x7fffu + ((i >> 16) & 1u);
  return (u16)(i >> 16);
}
__device__ __forceinline__ float bf2f(u16 u) {
  union { float f; unsigned int i; } x; x.i = ((unsigned int)u) << 16; return x.f;
}

union BF8 { short8 v; u16 u[8]; };
union BF4 { ushort4 v; u16 u[4]; };

// ---------- prep (once) ----------
__global__ __launch_bounds__(256) void kprep_w(
    const float* __restrict__ qW, const float* __restrict__ kW, const float* __restrict__ vW,
    u16* __restrict__ Wt)
{
  int idx = blockIdx.x*256 + threadIdx.x;     // (c, o, i)
  if (idx >= 3*DD*DD) return;
  int c = idx >> 18;
  int oi = idx & (DD*DD - 1);
  int i = oi & (DD-1);
  int o = oi >> 9;
  const float* W = (c==0) ? qW : (c==1) ? kW : vW;
  float w0 = W[oi*3+0], w1 = W[oi*3+1], w2 = W[oi*3+2];
  Wt[((size_t)(c*3+0)*DD + o)*DD + i] = f2bf(w0);
  Wt[((size_t)(c*3+1)*DD + o)*DD + i] = f2bf(w1);
  Wt[((size_t)(c*3+2)*DD + o)*DD + i] = f2bf(w2);
}

__global__ __launch_bounds__(256) void kcvt(const float* __restrict__ s, u16* __restrict__ d, int n) {
  int i = blockIdx.x*256 + threadIdx.x;
  if (i < n) d[i] = f2bf(s[i]);
}

__global__ __launch_bounds__(256) void kprep_a(
    const float* __restrict__ hW, const float* __restrict__ hai, const float* __restrict__ haib,
    const float* __restrict__ haj, const float* __restrict__ hajb,
    const float* __restrict__ hb,
    const float* __restrict__ oW, const float* __restrict__ oai, const float* __restrict__ oaib,
    const float* __restrict__ oaj, const float* __restrict__ oajb,
    const float* __restrict__ ob,
    float* __restrict__ ahat_i, float* __restrict__ ahat_j,
    float* __restrict__ oahat_i, float* __restrict__ oahat_j,
    float* __restrict__ cvec)
{
  int idx = blockIdx.x*256 + threadIdx.x;
  if (idx < 1024) {
    int h = idx >> 8, f = idx & 255;
    float s = 0.f;
    for (int o = 0; o < NHID; ++o) s += hW[((size_t)h*NHID + o)*WW + f] * hai[h*NHID + o];
    ahat_i[idx] = s;
  } else if (idx < 2048) {
    int t = idx - 1024; int h = t >> 8, f = t & 255;
    float s = 0.f;
    for (int o = 0; o < NHID; ++o) s += hW[((size_t)h*NHID + o)*WW + f] * haj[h*NHID + o];
    ahat_j[t] = s;
  } else if (idx < 2560) {
    int f = idx - 2048;
    float s = 0.f;
    for (int o = 0; o < WW; ++o) s += oW[(size_t)o*DD + f] * oai[o];
    oahat_i[f] = s;
  } else if (idx < 3072) {
    int f = idx - 2560;
    float s = 0.f;
    for (int o = 0; o < WW; ++o) s += oW[(size_t)o*DD + f] * oaj[o];
    oahat_j[f] = s;
  } else if (idx < 3082) {
    int t = idx - 3072;
    if (t < 4) {
      float s = 0.f;
      for (int o = 0; o < NHID; ++o) s += hb[t*NHID + o]*hai[t*NHID + o];
      cvec[t] = s + haib[t];
    } else if (t < 8) {
      int h = t - 4; float s = 0.f;
      for (int o = 0; o < NHID; ++o) s += hb[h*NHID + o]*haj[h*NHID + o];
      cvec[t] = s + hajb[h];
    } else if (t == 8) {
      float s = 0.f;
      for (int o = 0; o < WW; ++o) s += ob[o]*oai[o];
      cvec[8] = s + oaib[0];
    } else {
      float s = 0.f;
      for (int o = 0; o < WW; ++o) s += ob[o]*oaj[o];
      cvec[9] = s + oajb[0];
    }
  }
}

// x f32 -> xpad bf16 [z][258][512] with zero halo rows (t=-1, t=256)
__global__ __launch_bounds__(256) void kprep_x(
    const float* __restrict__ x, int zb, int nrow8, u16* __restrict__ xpad)
{
  int idx8 = blockIdx.x*256 + threadIdx.x;   // one short8 per thread
  if (idx8 >= nrow8) return;
  int i8 = idx8 & 63;
  int rowg = idx8 >> 6;                       // z*258 + r
  int z = rowg / 258, r = rowg - z*258;
  int t = r - 1;
  BF8 o8;
  if (t >= 0 && t < WW) {
    const float* src = x + ((size_t)(zb+z)*WW + t)*DD + i8*8;
    float4 v0 = *reinterpret_cast<const float4*>(src);
    float4 v1 = *reinterpret_cast<const float4*>(src + 4);
    o8.u[0]=f2bf(v0.x); o8.u[1]=f2bf(v0.y); o8.u[2]=f2bf(v0.z); o8.u[3]=f2bf(v0.w);
    o8.u[4]=f2bf(v1.x); o8.u[5]=f2bf(v1.y); o8.u[6]=f2bf(v1.z); o8.u[7]=f2bf(v1.w);
  } else {
    #pragma unroll
    for (int j = 0; j < 8; ++j) o8.u[j] = 0;
  }
  *reinterpret_cast<short8*>(xpad + (size_t)rowg*DD + i8*8) = o8.v;
}

// ---------- K1: conv via MFMA, padded x, P/Q register double-buffer ----------
__global__ __launch_bounds__(256) void k1_mfma(
    const u16* __restrict__ xpad, const u16* __restrict__ Wt,
    const float* __restrict__ qb, const float* __restrict__ kb, const float* __restrict__ vb,
    u16* __restrict__ qbf, u16* __restrict__ kbf, u16* __restrict__ vbf)
{
  const int w  = threadIdx.x >> 6;
  const int l  = threadIdx.x & 63;
  const int ln = l & 15;
  const int kg = l >> 4;
  const int og = blockIdx.x * 64 + w * 16;
  const int t0 = blockIdx.y * 64;
  const int z  = blockIdx.z;

  const u16* A0b = Wt + (size_t)(og + ln)*DD + kg*8;              // + c*3*DD*DD + tap*DD*DD + i0
  const u16* Bb  = xpad + ((size_t)z*258 + t0 + ln)*DD + kg*8;    // + (ts*16+tap)*DD + i0

  f32x4 acc[3][4];
  #pragma unroll
  for (int c=0;c<3;++c)
    #pragma unroll
    for (int ts=0;ts<4;++ts) acc[c][ts] = (f32x4){0.f,0.f,0.f,0.f};

  short8 Pa0,Pa1,Pa2, Pb0,Pb1,Pb2,Pb3;
  short8 Qa0,Qa1,Qa2, Qb0,Qb1,Qb2,Qb3;

#define K1_LD(Aa0,Aa1,Aa2,Bb0,Bb1,Bb2,Bb3, tapv, i0v) do { \
    Aa0 = *reinterpret_cast<const short8*>(A0b + (size_t)(tapv)*DD*DD + (i0v)); \
    Aa1 = *reinterpret_cast<const short8*>(A0b + (size_t)(3+(tapv))*DD*DD + (i0v)); \
    Aa2 = *reinterpret_cast<const short8*>(A0b + (size_t)(6+(tapv))*DD*DD + (i0v)); \
    Bb0 = *reinterpret_cast<const short8*>(Bb + (size_t)(0*16 + (tapv))*DD + (i0v)); \
    Bb1 = *reinterpret_cast<const short8*>(Bb + (size_t)(1*16 + (tapv))*DD + (i0v)); \
    Bb2 = *reinterpret_cast<const short8*>(Bb + (size_t)(2*16 + (tapv))*DD + (i0v)); \
    Bb3 = *reinterpret_cast<const short8*>(Bb + (size_t)(3*16 + (tapv))*DD + (i0v)); \
  } while(0)
#define K1_MM(Aa0,Aa1,Aa2,Bb0,Bb1,Bb2,Bb3) do { \
    acc[0][0] = __builtin_amdgcn_mfma_f32_16x16x32_bf16(Aa0, Bb0, acc[0][0], 0,0,0); \
    acc[0][1] = __builtin_amdgcn_mfma_f32_16x16x32_bf16(Aa0, Bb1, acc[0][1], 0,0,0); \
    acc[0][2] = __builtin_amdgcn_mfma_f32_16x16x32_bf16(Aa0, Bb2, acc[0][2], 0,0,0); \
    acc[0][3] = __builtin_amdgcn_mfma_f32_16x16x32_bf16(Aa0, Bb3, acc[0][3], 0,0,0); \
    acc[1][0] = __builtin_amdgcn_mfma_f32_16x16x32_bf16(Aa1, Bb0, acc[1][0], 0,0,0); \
    acc[1][1] = __builtin_amdgcn_mfma_f32_16x16x32_bf16(Aa1, Bb1, acc[1][1], 0,0,0); \
    acc[1][2] = __builtin_amdgcn_mfma_f32_16x16x32_bf16(Aa1, Bb2, acc[1][2], 0,0,0); \
    acc[1][3] = __builtin_amdgcn_mfma_f32_16x16x32_bf16(Aa1, Bb3, acc[1][3], 0,0,0); \
    acc[2][0] = __builtin_amdgcn_mfma_f32_16x16x32_bf16(Aa2, Bb0, acc[2][0], 0,0,0); \
    acc[2][1] = __builtin_amdgcn_mfma_f32_16x16x32_bf16(Aa2, Bb1, acc[2][1], 0,0,0); \
    acc[2][2] = __builtin_amdgcn_mfma_f32_16x16x32_bf16(Aa2, Bb2, acc[2][2], 0,0,0); \
    acc[2][3] = __builtin_amdgcn_mfma_f32_16x16x32_bf16(Aa2, Bb3, acc[2][3], 0,0,0); \
  } while(0)

  K1_LD(Pa0,Pa1,Pa2,Pb0,Pb1,Pb2,Pb3, 0, 0);
  for (int i0 = 0; i0 < 512; i0 += 64) {
    K1_LD(Qa0,Qa1,Qa2,Qb0,Qb1,Qb2,Qb3, 1, i0);
    K1_MM(Pa0,Pa1,Pa2,Pb0,Pb1,Pb2,Pb3);
    K1_LD(Pa0,Pa1,Pa2,Pb0,Pb1,Pb2,Pb3, 2, i0);
    K1_MM(Qa0,Qa1,Qa2,Qb0,Qb1,Qb2,Qb3);
    K1_LD(Qa0,Qa1,Qa2,Qb0,Qb1,Qb2,Qb3, 0, i0+32);
    K1_MM(Pa0,Pa1,Pa2,Pb0,Pb1,Pb2,Pb3);
    K1_LD(Pa0,Pa1,Pa2,Pb0,Pb1,Pb2,Pb3, 1, i0+32);
    K1_MM(Qa0,Qa1,Qa2,Qb0,Qb1,Qb2,Qb3);
    K1_LD(Qa0,Qa1,Qa2,Qb0,Qb1,Qb2,Qb3, 2, i0+32);
    K1_MM(Pa0,Pa1,Pa2,Pb0,Pb1,Pb2,Pb3);
    int nx = (i0+64 < 512) ? i0+64 : 0;
    K1_LD(Pa0,Pa1,Pa2,Pb0,Pb1,Pb2,Pb3, 0, nx);
    K1_MM(Qa0,Qa1,Qa2,Qb0,Qb1,Qb2,Qb3);
  }

  #pragma unroll
  for (int ts=0; ts<4; ++ts) {
    int tg = t0 + ts*16 + ln;
    #pragma unroll
    for (int r=0;r<4;++r) {
      int o = og + kg*4 + r;
      size_t oi = (size_t)(z*DD + o)*WW + tg;
      qbf[oi] = f2bf(acc[0][ts][r] + qb[o]);
      kbf[oi] = f2bf(acc[1][ts][r] + kb[o]);
      vbf[oi] = f2bf(acc[2][ts][r] + vb[o]);
    }
  }
}

// ---------- K2: adj = sigmoid(q.kT * scale) ----------
__global__ __launch_bounds__(256) void k2_adj(
    const u16* __restrict__ qbf, const u16* __restrict__ kbf, int zb, float* __restrict__ adjo)
{
  const int w = threadIdx.x >> 6, l = threadIdx.x & 63;
  const int ln = l & 15, kg = l >> 4;
  const int d0 = blockIdx.x*64 + w*16;
  const int e0 = blockIdx.y*64;
  const int z  = blockIdx.z;
  f32x4 acc[4];
  #pragma unroll
  for (int es=0;es<4;++es) acc[es] = (f32x4){0.f,0.f,0.f,0.f};
  for (int t0 = 0; t0 < WW; t0 += 32) {
    short8 a = *reinterpret_cast<const short8*>(qbf + ((size_t)(z*DD + d0 + ln)*WW + t0 + kg*8));
    #pragma unroll
    for (int es=0; es<4; ++es) {
      short8 b = *reinterpret_cast<const short8*>(kbf + ((size_t)(z*DD + e0 + es*16 + ln)*WW + t0 + kg*8));
      acc[es] = __builtin_amdgcn_mfma_f32_16x16x32_bf16(a, b, acc[es], 0,0,0);
    }
  }
  const float scale = 0.044194173824159216f;
  #pragma unroll
  for (int es=0; es<4; ++es)
    #pragma unroll
    for (int r=0; r<4; ++r) {
      float sig = 1.f/(1.f + expf(-acc[es][r]*scale));
      adjo[((size_t)(zb+z)*DD + d0 + kg*4 + r)*DD + e0 + es*16 + ln] = sig;
    }
}

// ---------- K3: Whtbf[zh][o][n] = (v @ hW^T + hb)^T bf16 ----------
__global__ __launch_bounds__(256) void k3_wh(
    const u16* __restrict__ vbf, const u16* __restrict__ hWbf, const float* __restrict__ hb,
    u16* __restrict__ Whtbf)
{
  const int w = threadIdx.x >> 6, l = threadIdx.x & 63;
  const int ln = l & 15, kg = l >> 4;
  const int n0 = blockIdx.x*64 + w*16;
  const int o0 = blockIdx.y*64;
  const int zh = blockIdx.z, z = zh >> 2, h = zh & 3;
  f32x4 acc[4];
  #pragma unroll
  for (int os=0;os<4;++os) acc[os] = (f32x4){0.f,0.f,0.f,0.f};
  for (int f0 = 0; f0 < WW; f0 += 32) {
    short8 a = *reinterpret_cast<const short8*>(vbf + ((size_t)(z*DD + n0 + ln)*WW + f0 + kg*8));
    #pragma unroll
    for (int os=0; os<4; ++os) {
      short8 b = *reinterpret_cast<const short8*>(hWbf + ((size_t)(h*NHID + o0 + os*16 + ln)*WW + f0 + kg*8));
      acc[os] = __builtin_amdgcn_mfma_f32_16x16x32_bf16(a, b, acc[os], 0,0,0);
    }
  }
  #pragma unroll
  for (int os=0; os<4; ++os)
    #pragma unroll
    for (int r=0; r<4; ++r) {
      int o = o0 + os*16 + ln;
      int n = n0 + kg*4 + r;
      Whtbf[((size_t)zh*NHID + o)*DD + n] = f2bf(acc[os][r] + hb[h*NHID + o]);
    }
}

// ---------- K4: e1h/e2h ----------
__global__ __launch_bounds__(256) void k4_eheads(
    const u16* __restrict__ vbf,
    const float* __restrict__ ahat_i, const float* __restrict__ ahat_j,
    const float* __restrict__ cvec,
    float* __restrict__ e1, float* __restrict__ e2)
{
  int row = blockIdx.x*4 + (threadIdx.x >> 6);   // row = zh*512 + n
  int lane = threadIdx.x & 63;
  int zh = row >> 9, n = row & 511;
  int z = zh >> 2, h = zh & 3;
  BF4 v4; v4.v = *reinterpret_cast<const ushort4*>(vbf + ((size_t)(z*DD + n))*WW + lane*4);
  const float* aif = ahat_i + h*WW + lane*4;
  const float* ajf = ahat_j + h*WW + lane*4;
  float a1 = 0.f, a2 = 0.f;
  #pragma unroll
  for (int j = 0; j < 4; ++j) {
    float vf = bf2f(v4.u[j]);
    a1 += vf * aif[j];
    a2 += vf * ajf[j];
  }
  #pragma unroll
  for (int off = 32; off >= 1; off >>= 1) { a1 += __shfl_xor(a1, off); a2 += __shfl_xor(a2, off); }
  if (lane == 0) { e1[row] = a1 + cvec[h]; e2[row] = a2 + cvec[4+h]; }
}

// ---------- K5: heads attention, prefetched PV ----------
__global__ __launch_bounds__(256) void k5_attn(
    const float* __restrict__ e1h, const float* __restrict__ e2h,
    const u16* __restrict__ Whtbf, u16* __restrict__ hcatbf)
{
  __shared__ u16 att[64*512];
  const int nb = blockIdx.x, zh = blockIdx.y;
  const int z = zh >> 2, h = zh & 3;
  const int n0 = nb*64;
  const int tid = threadIdx.x;

  const int r = tid >> 2, qd = tid & 3;
  const float e1n = e1h[(size_t)zh*DD + n0 + r];
  const float* e2r = e2h + (size_t)zh*DD + qd*128;
  float lmax = -1e30f;
  for (int j = 0; j < 128; ++j) {
    float e = e1n + e2r[j];
    e = (e > 0.f) ? e : 0.1f*e;
    lmax = fmaxf(lmax, e);
  }
  lmax = fmaxf(lmax, __shfl_xor(lmax, 1));
  lmax = fmaxf(lmax, __shfl_xor(lmax, 2));
  float lsum = 0.f;
  for (int jc = 0; jc < 16; ++jc) {
    BF8 pk;
    #pragma unroll
    for (int jj = 0; jj < 8; ++jj) {
      float e = e1n + e2r[jc*8 + jj];
      e = (e > 0.f) ? e : 0.1f*e;
      float p = expf(e - lmax);
      lsum += p;
      pk.u[jj] = f2bf(p);
    }
    int jc16 = qd*16 + jc;
    *reinterpret_cast<short8*>(&att[r*512 + ((jc16 ^ (r & 7)) << 3)]) = pk.v;
  }
  lsum += __shfl_xor(lsum, 1);
  lsum += __shfl_xor(lsum, 2);
  float inv_local = 1.f / lsum;
  __syncthreads();

  const int w = tid >> 6, l = tid & 63, ln = l & 15, kg = l >> 4;
  const int row = w*16 + ln;
  const u16* Bb = Whtbf + ((size_t)zh*NHID + ln)*DD + kg*8;
  f32x4 acc[8];
  #pragma unroll
  for (int os=0;os<8;++os) acc[os] = (f32x4){0.f,0.f,0.f,0.f};
  short8 P[8], Q[8];
  #pragma unroll
  for (int os=0; os<8; ++os) P[os] = *reinterpret_cast<const short8*>(Bb + (size_t)(os*16)*DD);
  for (int m0 = 0; m0 < 512; m0 += 64) {
    short8 a0 = *reinterpret_cast<const short8*>(&att[row*512 + ((((m0>>3)+kg) ^ (row & 7)) << 3)]);
    #pragma unroll
    for (int os=0; os<8; ++os) Q[os] = *reinterpret_cast<const short8*>(Bb + (size_t)(os*16)*DD + m0 + 32);
    #pragma unroll
    for (int os=0; os<8; ++os) acc[os] = __builtin_amdgcn_mfma_f32_16x16x32_bf16(a0, P[os], acc[os], 0,0,0);
    short8 a1 = *reinterpret_cast<const short8*>(&att[row*512 + ((((m0>>3)+4+kg) ^ (row & 7)) << 3)]);
    int nx = (m0+64 < 512) ? m0+64 : 0;
    #pragma unroll
    for (int os=0; os<8; ++os) P[os] = *reinterpret_cast<const short8*>(Bb + (size_t)(os*16)*DD + nx);
    #pragma unroll
    for (int os=0; os<8; ++os) acc[os] = __builtin_amdgcn_mfma_f32_16x16x32_bf16(a1, Q[os], acc[os], 0,0,0);
  }
  #pragma unroll
  for (int rr = 0; rr < 4; ++rr) {
    float inv = __shfl(inv_local, kg*16 + rr*4);
    int n = n0 + w*16 + kg*4 + rr;
    #pragma unroll
    for (int os = 0; os < 8; ++os) {
      float s = acc[os][rr] * inv;
      s = (s > 0.f) ? s : expm1f(s);
      hcatbf[((size_t)z*DD + n)*DD + h*NHID + os*16 + ln] = f2bf(s);
    }
  }
}

// ---------- K6: Wh2tbf[z][o][n] bf16 ----------
__global__ __launch_bounds__(256) void k6_wh2(
    const u16* __restrict__ hcatbf, const u16* __restrict__ oWbf, const float* __restrict__ ob,
    u16* __restrict__ Wh2tbf)
{
  const int w = threadIdx.x >> 6, l = threadIdx.x & 63;
  const int ln = l & 15, kg = l >> 4;
  const int n0 = blockIdx.x*64 + w*16;
  const int o0 = blockIdx.y*64;
  const int z  = blockIdx.z;
  f32x4 acc[4];
  #pragma unroll
  for (int os=0;os<4;++os) acc[os] = (f32x4){0.f,0.f,0.f,0.f};
  for (int f0 = 0; f0 < DD; f0 += 32) {
    short8 a = *reinterpret_cast<const short8*>(hcatbf + ((size_t)(z*DD + n0 + ln))*DD + f0 + kg*8);
    #pragma unroll
    for (int os=0; os<4; ++os) {
      short8 b = *reinterpret_cast<const short8*>(oWbf + (size_t)(o0 + os*16 + ln)*DD + f0 + kg*8);
      acc[os] = __builtin_amdgcn_mfma_f32_16x16x32_bf16(a, b, acc[os], 0,0,0);
    }
  }
  #pragma unroll
  for (int os=0; os<4; ++os)
    #pragma unroll
    for (int r=0; r<4; ++r) {
      int o = o0 + os*16 + ln;
      int n = n0 + kg*4 + r;
      Wh2tbf[((size_t)z*WW + o)*DD + n] = f2bf(acc[os][r] + ob[o]);
    }
}

// ---------- K7: e1o/e2o ----------
__global__ __launch_bounds__(256) void k7_eout(
    const u16* __restrict__ hcatbf,
    const float* __restrict__ oahat_i, const float* __restrict__ oahat_j,
    const float* __restrict__ cvec,
    float* __restrict__ e1, float* __restrict__ e2)
{
  int row = blockIdx.x*4 + (threadIdx.x >> 6);
  int lane = threadIdx.x & 63;
  BF8 v8; v8.v = *reinterpret_cast<const short8*>(hcatbf + (size_t)row*DD + lane*8);
  float a1 = 0.f, a2 = 0.f;
  #pragma unroll
  for (int j = 0; j < 8; ++j) {
    float vf = bf2f(v8.u[j]);
    a1 += vf * oahat_i[lane*8 + j];
    a2 += vf * oahat_j[lane*8 + j];
  }
  #pragma unroll
  for (int off = 32; off >= 1; off >>= 1) { a1 += __shfl_xor(a1, off); a2 += __shfl_xor(a2, off); }
  if (lane == 0) { e1[row] = a1 + cvec[8]; e2[row] = a2 + cvec[9]; }
}

// ---------- K8a: out attention PV (os split over blockIdx.z) -> g f32 (elu applied) ----------
__global__ __launch_bounds__(256) void k8_pv(
    const float* __restrict__ e1o, const float* __restrict__ e2o,
    const u16* __restrict__ Wh2tbf, float* __restrict__ g)
{
  __shared__ u16 att[64*512];
  const int nb = blockIdx.x, z = blockIdx.y, oh = blockIdx.z;
  const int n0 = nb*64;
  const int tid = threadIdx.x;

  const int r = tid >> 2, qd = tid & 3;
  const float e1n = e1o[(size_t)z*DD + n0 + r];
  const float* e2r = e2o + (size_t)z*DD + qd*128;
  float lmax = -1e30f;
  for (int j = 0; j < 128; ++j) {
    float e = e1n + e2r[j];
    e = (e > 0.f) ? e : 0.1f*e;
    lmax = fmaxf(lmax, e);
  }
  lmax = fmaxf(lmax, __shfl_xor(lmax, 1));
  lmax = fmaxf(lmax, __shfl_xor(lmax, 2));
  float lsum = 0.f;
  for (int jc = 0; jc < 16; ++jc) {
    BF8 pk;
    #pragma unroll
    for (int jj = 0; jj < 8; ++jj) {
      float e = e1n + e2r[jc*8 + jj];
      e = (e > 0.f) ? e : 0.1f*e;
      float p = expf(e - lmax);
      lsum += p;
      pk.u[jj] = f2bf(p);
    }
    int jc16 = qd*16 + jc;
    *reinterpret_cast<short8*>(&att[r*512 + ((jc16 ^ (r & 7)) << 3)]) = pk.v;
  }
  lsum += __shfl_xor(lsum, 1);
  lsum += __shfl_xor(lsum, 2);
  float inv_local = 1.f / lsum;
  __syncthreads();

  const int w = tid >> 6, l = tid & 63, ln = l & 15, kg = l >> 4;
  const int row = w*16 + ln;
  const u16* Bb = Wh2tbf + ((size_t)z*WW + oh*128 + ln)*DD + kg*8;
  f32x4 acc[8];
  #pragma unroll
  for (int os=0;os<8;++os) acc[os] = (f32x4){0.f,0.f,0.f,0.f};
  short8 P[8], Q[8];
  #pragma unroll
  for (int os=0; os<8; ++os) P[os] = *reinterpret_cast<const short8*>(Bb + (size_t)(os*16)*DD);
  for (int m0 = 0; m0 < 512; m0 += 64) {
    short8 a0 = *reinterpret_cast<const short8*>(&att[row*512 + ((((m0>>3)+kg) ^ (row & 7)) << 3)]);
    #pragma unroll
    for (int os=0; os<8; ++os) Q[os] = *reinterpret_cast<const short8*>(Bb + (size_t)(os*16)*DD + m0 + 32);
    #pragma unroll
    for (int os=0; os<8; ++os) acc[os] = __builtin_amdgcn_mfma_f32_16x16x32_bf16(a0, P[os], acc[os], 0,0,0);
    short8 a1 = *reinterpret_cast<const short8*>(&att[row*512 + ((((m0>>3)+4+kg) ^ (row & 7)) << 3)]);
    int nx = (m0+64 < 512) ? m0+64 : 0;
    #pragma unroll
    for (int os=0; os<8; ++os) P[os] = *reinterpret_cast<const short8*>(Bb + (size_t)(os*16)*DD + nx);
    #pragma unroll
    for (int os=0; os<8; ++os) acc[os] = __builtin_amdgcn_mfma_f32_16x16x32_bf16(a1, Q[os], acc[os], 0,0,0);
  }
  #pragma unroll
  for (int rr = 0; rr < 4; ++rr) {
    float inv = __shfl(inv_local, kg*16 + rr*4);
    int e = n0 + w*16 + kg*4 + rr;
    #pragma unroll
    for (int os = 0; os < 8; ++os) {
      float val = acc[os][rr] * inv;
      val = (val > 0.f) ? val : expm1f(val);    // elu
      g[((size_t)z*DD + e)*WW + oh*128 + os*16 + ln] = val;
    }
  }
}

// ---------- K8b: row log_softmax over o(256) -> gaty bf16 ----------
__global__ __launch_bounds__(256) void k8_lsm(
    const float* __restrict__ g, u16* __restrict__ gatybf)
{
  int row = blockIdx.x*4 + (threadIdx.x >> 6);
  int lane = threadIdx.x & 63;
  const float* gr = g + (size_t)row*WW;
  float v0 = gr[lane], v1 = gr[lane+64], v2 = gr[lane+128], v3 = gr[lane+192];
  float mx = fmaxf(fmaxf(v0,v1), fmaxf(v2,v3));
  #pragma unroll
  for (int off = 32; off >= 1; off >>= 1) mx = fmaxf(mx, __shfl_xor(mx, off));
  float sm = expf(v0-mx) + expf(v1-mx) + expf(v2-mx) + expf(v3-mx);
  #pragma unroll
  for (int off = 32; off >= 1; off >>= 1) sm += __shfl_xor(sm, off);
  float lg = mx + logf(sm);
  u16* go = gatybf + (size_t)row*WW;
  go[lane]     = f2bf(v0 - lg);
  go[lane+64]  = f2bf(v1 - lg);
  go[lane+128] = f2bf(v2 - lg);
  go[lane+192] = f2bf(v3 - lg);
}

// ---------- K9: out = gaty^T @ pW^T + pb ----------
__global__ __launch_bounds__(256) void k9_proj(
    const u16* __restrict__ gatybf, const u16* __restrict__ pWbf, const float* __restrict__ pb,
    int zb, float* __restrict__ out0)
{
  __shared__ u16 gt[64*40];
  const int t0 = blockIdx.x*64, d0 = blockIdx.y*64, z = blockIdx.z;
  const int tid = threadIdx.x;
  const int w = tid >> 6, l = tid & 63, ln = l & 15, kg = l >> 4;
  const int el = tid >> 3, t8 = tid & 7;
  f32x4 acc[4];
  #pragma unroll
  for (int os=0;os<4;++os) acc[os] = (f32x4){0.f,0.f,0.f,0.f};
  for (int e0 = 0; e0 < DD; e0 += 32) {
    __syncthreads();
    BF8 g8;
    g8.v = *reinterpret_cast<const short8*>(gatybf + ((size_t)z*DD + e0 + el)*WW + t0 + t8*8);
    #pragma unroll
    for (int j = 0; j < 8; ++j) gt[(t8*8 + j)*40 + el] = g8.u[j];
    __syncthreads();
    short8 a = *reinterpret_cast<const short8*>(&gt[(w*16 + ln)*40 + kg*8]);
    #pragma unroll
    for (int os = 0; os < 4; ++os) {
      short8 b = *reinterpret_cast<const short8*>(pWbf + (size_t)(d0 + os*16 + ln)*DD + e0 + kg*8);
      acc[os] = __builtin_amdgcn_mfma_f32_16x16x32_bf16(a, b, acc[os], 0,0,0);
    }
  }
  #pragma unroll
  for (int os=0; os<4; ++os)
    #pragma unroll
    for (int rr=0; rr<4; ++rr) {
      int t = t0 + w*16 + kg*4 + rr;
      int d = d0 + os*16 + ln;
      out0[((size_t)(zb+z)*WW + t)*DD + d] = acc[os][rr] + pb[d];
    }
}

extern "C" void kernel_launch(void* const* d_in, const int* in_sizes, int n_in,
                              void* d_out, int out_size, void* d_ws, size_t ws_size,
                              hipStream_t stream)
{
  const float* x   = (const float*)d_in[0];
  const float* qW  = (const float*)d_in[1];
  const float* qb  = (const float*)d_in[2];
  const float* kW  = (const float*)d_in[3];
  const float* kb  = (const float*)d_in[4];
  const float* vW  = (const float*)d_in[5];
  const float* vb  = (const float*)d_in[6];
  const float* hW  = (const float*)d_in[7];
  const float* hb  = (const float*)d_in[8];
  const float* hai = (const float*)d_in[9];
  const float* haib= (const float*)d_in[10];
  const float* haj = (const float*)d_in[11];
  const float* hajb= (const float*)d_in[12];
  const float* oW  = (const float*)d_in[13];
  const float* ob  = (const float*)d_in[14];
  const float* oai = (const float*)d_in[15];
  const float* oaib= (const float*)d_in[16];
  const float* oaj = (const float*)d_in[17];
  const float* oajb= (const float*)d_in[18];
  const float* pW  = (const float*)d_in[19];
  const float* pb  = (const float*)d_in[20];

  float* out0 = (float*)d_out;                   // [B,W,D] f32
  float* adjo = out0 + (size_t)BB*WW*DD;         // [B,D,D] f32

  // static region (float offsets)
  float* ws      = (float*)d_ws;
  u16*   Wt      = (u16*)(ws + 0);           // 1,179,648 f
  u16*   hWbf    = (u16*)(ws + 1179648);     //    65,536 f
  u16*   oWbf    = (u16*)(ws + 1245184);     //    65,536 f
  u16*   pWbf    = (u16*)(ws + 1310720);     //   131,072 f
  float* ahat_i  = ws + 1441792;
  float* ahat_j  = ws + 1442816;
  float* oahat_i = ws + 1443840;
  float* oahat_j = ws + 1444352;
  float* cvec    = ws + 1444864;
  float* e1h     = ws + 1444880;             //    65,536 f (CB=32 max)
  float* e2h     = ws + 1510416;
  float* e1o     = ws + 1575952;             //    16,384 f
  float* e2o     = ws + 1592336;
  const size_t X0 = 1608720;                 // dynamic region start

  // per-CB dynamic: xpad 66,048 + vbf 65,536 + qbf 65,536 + kbf 65,536 + Whtbf 131,072 = 393,728 f
  int CB = 4;
  {
    const int cand[3] = {32, 16, 8};
    for (int i = 0; i < 3; ++i) {
      size_t need = (X0 + (size_t)cand[i]*393728) * 4;
      if (need <= ws_size) { CB = cand[i]; break; }
    }
  }

  u16* xpad   = (u16*)(ws + X0);                        // CB*66,048 f  ([z][258][512])
  u16* vbf    = (u16*)(ws + X0 + (size_t)CB*66048);     // CB*65,536 f
  u16* qbf    = (u16*)(ws + X0 + (size_t)CB*131584);    // CB*65,536 f
  u16* kbf    = (u16*)(ws + X0 + (size_t)CB*197120);    // CB*65,536 f
  u16* Whtbf  = (u16*)(ws + X0 + (size_t)CB*262656);    // CB*131,072 f
  // overlays (lifetimes: xpad dead after k1; vbf dead after k4; qbf,kbf dead after k2;
  // hcatbf dead after k7; Whtbf dead after k5)
  u16*   hcatbf = (u16*)(ws + X0);                      // over xpad+vbf (CB*131,584 f >= CB*131,072)
  float* g      = (float*)(ws + X0);                    // over hcatbf region (k8 phase)
  u16*   gatybf = (u16*)(ws + X0 + (size_t)CB*131584);  // over qbf
  u16*   Wh2tbf = (u16*)(ws + X0 + (size_t)CB*197120);  // over kbf

  kprep_w<<<dim3((3*DD*DD + 255)/256), 256, 0, stream>>>(qW, kW, vW, Wt);
  kcvt<<<dim3((NHEADS*NHID*WW + 255)/256), 256, 0, stream>>>(hW, hWbf, NHEADS*NHID*WW);
  kcvt<<<dim3((WW*DD + 255)/256), 256, 0, stream>>>(oW, oWbf, WW*DD);
  kcvt<<<dim3((DD*DD + 255)/256), 256, 0, stream>>>(pW, pWbf, DD*DD);
  kprep_a<<<dim3(13), 256, 0, stream>>>(hW, hai, haib, haj, hajb, hb,
                                        oW, oai, oaib, oaj, oajb, ob,
                                        ahat_i, ahat_j, oahat_i, oahat_j, cvec);

  for (int zb = 0; zb < BB; zb += CB) {
    int nrow8 = CB*258*64;
    kprep_x  <<<dim3((nrow8 + 255)/256), 256, 0, stream>>>(x, zb, nrow8, xpad);
    k1_mfma  <<<dim3(DD/64, WW/64, CB), 256, 0, stream>>>(xpad, Wt, qb, kb, vb, qbf, kbf, vbf);
    k2_adj   <<<dim3(DD/64, DD/64, CB), 256, 0, stream>>>(qbf, kbf, zb, adjo);
    k3_wh    <<<dim3(DD/64, NHID/64, CB*NHEADS), 256, 0, stream>>>(vbf, hWbf, hb, Whtbf);
    k4_eheads<<<dim3(CB*NHEADS*DD/4), 256, 0, stream>>>(vbf, ahat_i, ahat_j, cvec, e1h, e2h);
    k5_attn  <<<dim3(DD/64, CB*NHEADS), 256, 0, stream>>>(e1h, e2h, Whtbf, hcatbf);
    k6_wh2   <<<dim3(DD/64, WW/64, CB), 256, 0, stream>>>(hcatbf, oWbf, ob, Wh2tbf);
    k7_eout  <<<dim3(CB*DD/4), 256, 0, stream>>>(hcatbf, oahat_i, oahat_j, cvec, e1o, e2o);
    k8_pv    <<<dim3(DD/64, CB, 2), 256, 0, stream>>>(e1o, e2o, Wh2tbf, g);
    k8_lsm   <<<dim3(CB*128), 256, 0, stream>>>(g, gatybf);
    k9_proj  <<<dim3(WW/64, DD/64, CB), 256, 0, stream>>>(gatybf, pWbf, pb, zb, out0);
  }
}

// Round 10
// 459.795 us; speedup vs baseline: 1.1629x; 1.1629x over previous
//
#include <hip/hip_runtime.h>
#include <math.h>

typedef unsigned short u16;
typedef __attribute__((ext_vector_type(8))) short short8;
typedef __attribute__((ext_vector_type(4))) float f32x4;

#define BB 32
#define WW 256
#define DD 512
#define NHEADS 4
#define NHID 128

__device__ __forceinline__ u16 f2bf(float f) {
  union { float f; unsigned int i; } x; x.f = f;
  unsigned int i = x.i;
  i += 0x7fffu + ((i >> 16) & 1u);
  return (u16)(i >> 16);
}
__device__ __forceinline__ float bf2f(u16 u) {
  union { float f; unsigned int i; } x; x.i = ((unsigned int)u) << 16; return x.f;
}

union BF8 { short8 v; u16 u[8]; };
union BF4 { ushort4 v; u16 u[4]; };

// ---------- prep (once) ----------
__global__ __launch_bounds__(256) void kprep_w(
    const float* __restrict__ qW, const float* __restrict__ kW, const float* __restrict__ vW,
    u16* __restrict__ Wt)
{
  int idx = blockIdx.x*256 + threadIdx.x;     // (c, o, i)
  if (idx >= 3*DD*DD) return;
  int c = idx >> 18;
  int oi = idx & (DD*DD - 1);
  int i = oi & (DD-1);
  int o = oi >> 9;
  const float* W = (c==0) ? qW : (c==1) ? kW : vW;
  float w0 = W[oi*3+0], w1 = W[oi*3+1], w2 = W[oi*3+2];
  Wt[((size_t)(c*3+0)*DD + o)*DD + i] = f2bf(w0);
  Wt[((size_t)(c*3+1)*DD + o)*DD + i] = f2bf(w1);
  Wt[((size_t)(c*3+2)*DD + o)*DD + i] = f2bf(w2);
}

__global__ __launch_bounds__(256) void kcvt(const float* __restrict__ s, u16* __restrict__ d, int n) {
  int i = blockIdx.x*256 + threadIdx.x;
  if (i < n) d[i] = f2bf(s[i]);
}

__global__ __launch_bounds__(256) void kprep_a(
    const float* __restrict__ hW, const float* __restrict__ hai, const float* __restrict__ haib,
    const float* __restrict__ haj, const float* __restrict__ hajb,
    const float* __restrict__ hb,
    const float* __restrict__ oW, const float* __restrict__ oai, const float* __restrict__ oaib,
    const float* __restrict__ oaj, const float* __restrict__ oajb,
    const float* __restrict__ ob,
    float* __restrict__ ahat_i, float* __restrict__ ahat_j,
    float* __restrict__ oahat_i, float* __restrict__ oahat_j,
    float* __restrict__ cvec)
{
  int idx = blockIdx.x*256 + threadIdx.x;
  if (idx < 1024) {
    int h = idx >> 8, f = idx & 255;
    float s = 0.f;
    for (int o = 0; o < NHID; ++o) s += hW[((size_t)h*NHID + o)*WW + f] * hai[h*NHID + o];
    ahat_i[idx] = s;
  } else if (idx < 2048) {
    int t = idx - 1024; int h = t >> 8, f = t & 255;
    float s = 0.f;
    for (int o = 0; o < NHID; ++o) s += hW[((size_t)h*NHID + o)*WW + f] * haj[h*NHID + o];
    ahat_j[t] = s;
  } else if (idx < 2560) {
    int f = idx - 2048;
    float s = 0.f;
    for (int o = 0; o < WW; ++o) s += oW[(size_t)o*DD + f] * oai[o];
    oahat_i[f] = s;
  } else if (idx < 3072) {
    int f = idx - 2560;
    float s = 0.f;
    for (int o = 0; o < WW; ++o) s += oW[(size_t)o*DD + f] * oaj[o];
    oahat_j[f] = s;
  } else if (idx < 3082) {
    int t = idx - 3072;
    if (t < 4) {
      float s = 0.f;
      for (int o = 0; o < NHID; ++o) s += hb[t*NHID + o]*hai[t*NHID + o];
      cvec[t] = s + haib[t];
    } else if (t < 8) {
      int h = t - 4; float s = 0.f;
      for (int o = 0; o < NHID; ++o) s += hb[h*NHID + o]*haj[h*NHID + o];
      cvec[t] = s + hajb[h];
    } else if (t == 8) {
      float s = 0.f;
      for (int o = 0; o < WW; ++o) s += ob[o]*oai[o];
      cvec[8] = s + oaib[0];
    } else {
      float s = 0.f;
      for (int o = 0; o < WW; ++o) s += ob[o]*oaj[o];
      cvec[9] = s + oajb[0];
    }
  }
}

// x f32 -> xpad bf16 [z][258][512] with zero halo rows (t=-1, t=256)
__global__ __launch_bounds__(256) void kprep_x(
    const float* __restrict__ x, int zb, int nrow8, u16* __restrict__ xpad)
{
  int idx8 = blockIdx.x*256 + threadIdx.x;
  if (idx8 >= nrow8) return;
  int i8 = idx8 & 63;
  int rowg = idx8 >> 6;                       // z*258 + r
  int z = rowg / 258, r = rowg - z*258;
  int t = r - 1;
  BF8 o8;
  if (t >= 0 && t < WW) {
    const float* src = x + ((size_t)(zb+z)*WW + t)*DD + i8*8;
    float4 v0 = *reinterpret_cast<const float4*>(src);
    float4 v1 = *reinterpret_cast<const float4*>(src + 4);
    o8.u[0]=f2bf(v0.x); o8.u[1]=f2bf(v0.y); o8.u[2]=f2bf(v0.z); o8.u[3]=f2bf(v0.w);
    o8.u[4]=f2bf(v1.x); o8.u[5]=f2bf(v1.y); o8.u[6]=f2bf(v1.z); o8.u[7]=f2bf(v1.w);
  } else {
    #pragma unroll
    for (int j = 0; j < 8; ++j) o8.u[j] = 0;
  }
  *reinterpret_cast<short8*>(xpad + (size_t)rowg*DD + i8*8) = o8.v;
}

// ---------- K1: conv via MFMA; B tile LDS-staged (swizzled, dbuf), A reg-prefetched ----------
__global__ __launch_bounds__(256) void k1_mfma(
    const u16* __restrict__ xpad, const u16* __restrict__ Wt,
    const float* __restrict__ qb, const float* __restrict__ kb, const float* __restrict__ vb,
    u16* __restrict__ qbf, u16* __restrict__ kbf, u16* __restrict__ vbf)
{
  __shared__ u16 bt[2][66*64];               // 16.9 KB: [buf][row][i-chunk swizzled]
  const int tid = threadIdx.x;
  const int w  = tid >> 6;
  const int l  = tid & 63;
  const int ln = l & 15;
  const int kg = l >> 4;
  const int og = blockIdx.x * 64 + w * 16;
  const int t0 = blockIdx.y * 64;
  const int z  = blockIdx.z;

  const u16* A0 = Wt + (size_t)(og + ln)*DD + kg*8;        // + (c*3+tap)*DD*DD + i
  const u16* Xb = xpad + ((size_t)z*258 + t0)*DD;          // tile row r = xpad row t0+r

  f32x4 acc[3][4];
  #pragma unroll
  for (int c=0;c<3;++c)
    #pragma unroll
    for (int ts=0;ts<4;++ts) acc[c][ts] = (f32x4){0.f,0.f,0.f,0.f};

  short8 ArP[9], ArQ[9];        // A buffers for kh=0 / kh=1 phases (static names: no scratch)
  short8 sreg0, sreg1, sreg2;   // staging regs for next B tile

  const int ccw = tid & 7;
  const int r0s = tid >> 3, r1s = (tid+256) >> 3, r2s = (tid+512) >> 3;

#define K1_LOADX(i0v) do { \
    sreg0 = *reinterpret_cast<const short8*>(Xb + (size_t)r0s*DD + (i0v) + ccw*8); \
    sreg1 = *reinterpret_cast<const short8*>(Xb + (size_t)r1s*DD + (i0v) + ccw*8); \
    if (tid < 16) sreg2 = *reinterpret_cast<const short8*>(Xb + (size_t)r2s*DD + (i0v) + ccw*8); \
  } while(0)

#define K1_WRITEX(bufv) do { \
    *reinterpret_cast<short8*>(&bt[bufv][r0s*64 + ((ccw^(r0s&7))<<3)]) = sreg0; \
    *reinterpret_cast<short8*>(&bt[bufv][r1s*64 + ((ccw^(r1s&7))<<3)]) = sreg1; \
    if (tid < 16) *reinterpret_cast<short8*>(&bt[bufv][r2s*64 + ((ccw^(r2s&7))<<3)]) = sreg2; \
  } while(0)

#define K1_LOADA(Abuf, i0v, khv) do { \
    _Pragma("unroll") \
    for (int c = 0; c < 3; ++c) { \
      _Pragma("unroll") \
      for (int tap = 0; tap < 3; ++tap) \
        Abuf[c*3+tap] = *reinterpret_cast<const short8*>(A0 + (size_t)(c*3+tap)*DD*DD + (i0v) + (khv)*32); \
    } \
  } while(0)

#define K1_MFMAS(Abuf, khv) do { \
    _Pragma("unroll") \
    for (int tap = 0; tap < 3; ++tap) { \
      _Pragma("unroll") \
      for (int ts = 0; ts < 4; ++ts) { \
        int row = ts*16 + ln + tap; \
        short8 bfr = *reinterpret_cast<const short8*>(&bt[cur][row*64 + ((((khv)*4+kg) ^ (row&7))<<3)]); \
        acc[0][ts] = __builtin_amdgcn_mfma_f32_16x16x32_bf16(Abuf[0*3+tap], bfr, acc[0][ts], 0,0,0); \
        acc[1][ts] = __builtin_amdgcn_mfma_f32_16x16x32_bf16(Abuf[1*3+tap], bfr, acc[1][ts], 0,0,0); \
        acc[2][ts] = __builtin_amdgcn_mfma_f32_16x16x32_bf16(Abuf[2*3+tap], bfr, acc[2][ts], 0,0,0); \
      } \
    } \
  } while(0)

  // prologue: stage tile 0, preload A(kh=0)
  K1_LOADX(0);
  K1_LOADA(ArP, 0, 0);
  K1_WRITEX(0);
  __syncthreads();

  int cur = 0;
  #pragma unroll 1
  for (int p = 0; p < 8; ++p) {             // tile pair p: i0 = p*64
    const int i0 = p*64;
    if (p < 7) K1_LOADX(i0 + 64);           // global loads for next tile (consumed at pair end)
    K1_LOADA(ArQ, i0, 1);                   // A for kh=1 phase
    K1_MFMAS(ArP, 0);                       // 36 MFMAs, kh=0
    const int i0n = (p < 7) ? i0 + 64 : 0;
    K1_LOADA(ArP, i0n, 0);                  // A for next pair's kh=0 (harmless reload at end)
    K1_MFMAS(ArQ, 1);                       // 36 MFMAs, kh=1
    if (p < 7) {
      K1_WRITEX(cur ^ 1);                   // write next tile (sregs loaded this pair)
      __syncthreads();
      cur ^= 1;
    }
  }

#undef K1_LOADX
#undef K1_WRITEX
#undef K1_LOADA
#undef K1_MFMAS

  #pragma unroll
  for (int ts=0; ts<4; ++ts) {
    int tg = t0 + ts*16 + ln;
    #pragma unroll
    for (int r=0;r<4;++r) {
      int o = og + kg*4 + r;
      size_t oi = (size_t)(z*DD + o)*WW + tg;
      qbf[oi] = f2bf(acc[0][ts][r] + qb[o]);
      kbf[oi] = f2bf(acc[1][ts][r] + kb[o]);
      vbf[oi] = f2bf(acc[2][ts][r] + vb[o]);
    }
  }
}

// ---------- K2: adj = sigmoid(q.kT * scale) ----------
__global__ __launch_bounds__(256) void k2_adj(
    const u16* __restrict__ qbf, const u16* __restrict__ kbf, int zb, float* __restrict__ adjo)
{
  const int w = threadIdx.x >> 6, l = threadIdx.x & 63;
  const int ln = l & 15, kg = l >> 4;
  const int d0 = blockIdx.x*64 + w*16;
  const int e0 = blockIdx.y*64;
  const int z  = blockIdx.z;
  f32x4 acc[4];
  #pragma unroll
  for (int es=0;es<4;++es) acc[es] = (f32x4){0.f,0.f,0.f,0.f};
  for (int t0 = 0; t0 < WW; t0 += 32) {
    short8 a = *reinterpret_cast<const short8*>(qbf + ((size_t)(z*DD + d0 + ln)*WW + t0 + kg*8));
    #pragma unroll
    for (int es=0; es<4; ++es) {
      short8 b = *reinterpret_cast<const short8*>(kbf + ((size_t)(z*DD + e0 + es*16 + ln)*WW + t0 + kg*8));
      acc[es] = __builtin_amdgcn_mfma_f32_16x16x32_bf16(a, b, acc[es], 0,0,0);
    }
  }
  const float scale = 0.044194173824159216f;
  #pragma unroll
  for (int es=0; es<4; ++es)
    #pragma unroll
    for (int r=0; r<4; ++r) {
      float sig = 1.f/(1.f + expf(-acc[es][r]*scale));
      adjo[((size_t)(zb+z)*DD + d0 + kg*4 + r)*DD + e0 + es*16 + ln] = sig;
    }
}

// ---------- K3: Whtbf[zh][o][n] = (v @ hW^T + hb)^T bf16 ----------
__global__ __launch_bounds__(256) void k3_wh(
    const u16* __restrict__ vbf, const u16* __restrict__ hWbf, const float* __restrict__ hb,
    u16* __restrict__ Whtbf)
{
  const int w = threadIdx.x >> 6, l = threadIdx.x & 63;
  const int ln = l & 15, kg = l >> 4;
  const int n0 = blockIdx.x*64 + w*16;
  const int o0 = blockIdx.y*64;
  const int zh = blockIdx.z, z = zh >> 2, h = zh & 3;
  f32x4 acc[4];
  #pragma unroll
  for (int os=0;os<4;++os) acc[os] = (f32x4){0.f,0.f,0.f,0.f};
  for (int f0 = 0; f0 < WW; f0 += 32) {
    short8 a = *reinterpret_cast<const short8*>(vbf + ((size_t)(z*DD + n0 + ln)*WW + f0 + kg*8));
    #pragma unroll
    for (int os=0; os<4; ++os) {
      short8 b = *reinterpret_cast<const short8*>(hWbf + ((size_t)(h*NHID + o0 + os*16 + ln)*WW + f0 + kg*8));
      acc[os] = __builtin_amdgcn_mfma_f32_16x16x32_bf16(a, b, acc[os], 0,0,0);
    }
  }
  #pragma unroll
  for (int os=0; os<4; ++os)
    #pragma unroll
    for (int r=0; r<4; ++r) {
      int o = o0 + os*16 + ln;
      int n = n0 + kg*4 + r;
      Whtbf[((size_t)zh*NHID + o)*DD + n] = f2bf(acc[os][r] + hb[h*NHID + o]);
    }
}

// ---------- K4: e1h/e2h ----------
__global__ __launch_bounds__(256) void k4_eheads(
    const u16* __restrict__ vbf,
    const float* __restrict__ ahat_i, const float* __restrict__ ahat_j,
    const float* __restrict__ cvec,
    float* __restrict__ e1, float* __restrict__ e2)
{
  int row = blockIdx.x*4 + (threadIdx.x >> 6);   // row = zh*512 + n
  int lane = threadIdx.x & 63;
  int zh = row >> 9, n = row & 511;
  int z = zh >> 2, h = zh & 3;
  BF4 v4; v4.v = *reinterpret_cast<const ushort4*>(vbf + ((size_t)(z*DD + n))*WW + lane*4);
  const float* aif = ahat_i + h*WW + lane*4;
  const float* ajf = ahat_j + h*WW + lane*4;
  float a1 = 0.f, a2 = 0.f;
  #pragma unroll
  for (int j = 0; j < 4; ++j) {
    float vf = bf2f(v4.u[j]);
    a1 += vf * aif[j];
    a2 += vf * ajf[j];
  }
  #pragma unroll
  for (int off = 32; off >= 1; off >>= 1) { a1 += __shfl_xor(a1, off); a2 += __shfl_xor(a2, off); }
  if (lane == 0) { e1[row] = a1 + cvec[h]; e2[row] = a2 + cvec[4+h]; }
}

// ---------- K5: heads attention, prefetched PV ----------
__global__ __launch_bounds__(256) void k5_attn(
    const float* __restrict__ e1h, const float* __restrict__ e2h,
    const u16* __restrict__ Whtbf, u16* __restrict__ hcatbf)
{
  __shared__ u16 att[64*512];
  const int nb = blockIdx.x, zh = blockIdx.y;
  const int z = zh >> 2, h = zh & 3;
  const int n0 = nb*64;
  const int tid = threadIdx.x;

  const int r = tid >> 2, qd = tid & 3;
  const float e1n = e1h[(size_t)zh*DD + n0 + r];
  const float* e2r = e2h + (size_t)zh*DD + qd*128;
  float lmax = -1e30f;
  for (int j = 0; j < 128; ++j) {
    float e = e1n + e2r[j];
    e = (e > 0.f) ? e : 0.1f*e;
    lmax = fmaxf(lmax, e);
  }
  lmax = fmaxf(lmax, __shfl_xor(lmax, 1));
  lmax = fmaxf(lmax, __shfl_xor(lmax, 2));
  float lsum = 0.f;
  for (int jc = 0; jc < 16; ++jc) {
    BF8 pk;
    #pragma unroll
    for (int jj = 0; jj < 8; ++jj) {
      float e = e1n + e2r[jc*8 + jj];
      e = (e > 0.f) ? e : 0.1f*e;
      float p = expf(e - lmax);
      lsum += p;
      pk.u[jj] = f2bf(p);
    }
    int jc16 = qd*16 + jc;
    *reinterpret_cast<short8*>(&att[r*512 + ((jc16 ^ (r & 7)) << 3)]) = pk.v;
  }
  lsum += __shfl_xor(lsum, 1);
  lsum += __shfl_xor(lsum, 2);
  float inv_local = 1.f / lsum;
  __syncthreads();

  const int w = tid >> 6, l = tid & 63, ln = l & 15, kg = l >> 4;
  const int row = w*16 + ln;
  const u16* Bb = Whtbf + ((size_t)zh*NHID + ln)*DD + kg*8;
  f32x4 acc[8];
  #pragma unroll
  for (int os=0;os<8;++os) acc[os] = (f32x4){0.f,0.f,0.f,0.f};
  short8 P[8], Q[8];
  #pragma unroll
  for (int os=0; os<8; ++os) P[os] = *reinterpret_cast<const short8*>(Bb + (size_t)(os*16)*DD);
  for (int m0 = 0; m0 < 512; m0 += 64) {
    short8 a0 = *reinterpret_cast<const short8*>(&att[row*512 + ((((m0>>3)+kg) ^ (row & 7)) << 3)]);
    #pragma unroll
    for (int os=0; os<8; ++os) Q[os] = *reinterpret_cast<const short8*>(Bb + (size_t)(os*16)*DD + m0 + 32);
    #pragma unroll
    for (int os=0; os<8; ++os) acc[os] = __builtin_amdgcn_mfma_f32_16x16x32_bf16(a0, P[os], acc[os], 0,0,0);
    short8 a1 = *reinterpret_cast<const short8*>(&att[row*512 + ((((m0>>3)+4+kg) ^ (row & 7)) << 3)]);
    int nx = (m0+64 < 512) ? m0+64 : 0;
    #pragma unroll
    for (int os=0; os<8; ++os) P[os] = *reinterpret_cast<const short8*>(Bb + (size_t)(os*16)*DD + nx);
    #pragma unroll
    for (int os=0; os<8; ++os) acc[os] = __builtin_amdgcn_mfma_f32_16x16x32_bf16(a1, Q[os], acc[os], 0,0,0);
  }
  #pragma unroll
  for (int rr = 0; rr < 4; ++rr) {
    float inv = __shfl(inv_local, kg*16 + rr*4);
    int n = n0 + w*16 + kg*4 + rr;
    #pragma unroll
    for (int os = 0; os < 8; ++os) {
      float s = acc[os][rr] * inv;
      s = (s > 0.f) ? s : expm1f(s);
      hcatbf[((size_t)z*DD + n)*DD + h*NHID + os*16 + ln] = f2bf(s);
    }
  }
}

// ---------- K6: Wh2tbf[z][o][n] bf16 ----------
__global__ __launch_bounds__(256) void k6_wh2(
    const u16* __restrict__ hcatbf, const u16* __restrict__ oWbf, const float* __restrict__ ob,
    u16* __restrict__ Wh2tbf)
{
  const int w = threadIdx.x >> 6, l = threadIdx.x & 63;
  const int ln = l & 15, kg = l >> 4;
  const int n0 = blockIdx.x*64 + w*16;
  const int o0 = blockIdx.y*64;
  const int z  = blockIdx.z;
  f32x4 acc[4];
  #pragma unroll
  for (int os=0;os<4;++os) acc[os] = (f32x4){0.f,0.f,0.f,0.f};
  for (int f0 = 0; f0 < DD; f0 += 32) {
    short8 a = *reinterpret_cast<const short8*>(hcatbf + ((size_t)(z*DD + n0 + ln))*DD + f0 + kg*8);
    #pragma unroll
    for (int os=0; os<4; ++os) {
      short8 b = *reinterpret_cast<const short8*>(oWbf + (size_t)(o0 + os*16 + ln)*DD + f0 + kg*8);
      acc[os] = __builtin_amdgcn_mfma_f32_16x16x32_bf16(a, b, acc[os], 0,0,0);
    }
  }
  #pragma unroll
  for (int os=0; os<4; ++os)
    #pragma unroll
    for (int r=0; r<4; ++r) {
      int o = o0 + os*16 + ln;
      int n = n0 + kg*4 + r;
      Wh2tbf[((size_t)z*WW + o)*DD + n] = f2bf(acc[os][r] + ob[o]);
    }
}

// ---------- K7: e1o/e2o ----------
__global__ __launch_bounds__(256) void k7_eout(
    const u16* __restrict__ hcatbf,
    const float* __restrict__ oahat_i, const float* __restrict__ oahat_j,
    const float* __restrict__ cvec,
    float* __restrict__ e1, float* __restrict__ e2)
{
  int row = blockIdx.x*4 + (threadIdx.x >> 6);
  int lane = threadIdx.x & 63;
  BF8 v8; v8.v = *reinterpret_cast<const short8*>(hcatbf + (size_t)row*DD + lane*8);
  float a1 = 0.f, a2 = 0.f;
  #pragma unroll
  for (int j = 0; j < 8; ++j) {
    float vf = bf2f(v8.u[j]);
    a1 += vf * oahat_i[lane*8 + j];
    a2 += vf * oahat_j[lane*8 + j];
  }
  #pragma unroll
  for (int off = 32; off >= 1; off >>= 1) { a1 += __shfl_xor(a1, off); a2 += __shfl_xor(a2, off); }
  if (lane == 0) { e1[row] = a1 + cvec[8]; e2[row] = a2 + cvec[9]; }
}

// ---------- K8a: out attention PV (os split over blockIdx.z) -> g f32 (elu applied) ----------
__global__ __launch_bounds__(256) void k8_pv(
    const float* __restrict__ e1o, const float* __restrict__ e2o,
    const u16* __restrict__ Wh2tbf, float* __restrict__ g)
{
  __shared__ u16 att[64*512];
  const int nb = blockIdx.x, z = blockIdx.y, oh = blockIdx.z;
  const int n0 = nb*64;
  const int tid = threadIdx.x;

  const int r = tid >> 2, qd = tid & 3;
  const float e1n = e1o[(size_t)z*DD + n0 + r];
  const float* e2r = e2o + (size_t)z*DD + qd*128;
  float lmax = -1e30f;
  for (int j = 0; j < 128; ++j) {
    float e = e1n + e2r[j];
    e = (e > 0.f) ? e : 0.1f*e;
    lmax = fmaxf(lmax, e);
  }
  lmax = fmaxf(lmax, __shfl_xor(lmax, 1));
  lmax = fmaxf(lmax, __shfl_xor(lmax, 2));
  float lsum = 0.f;
  for (int jc = 0; jc < 16; ++jc) {
    BF8 pk;
    #pragma unroll
    for (int jj = 0; jj < 8; ++jj) {
      float e = e1n + e2r[jc*8 + jj];
      e = (e > 0.f) ? e : 0.1f*e;
      float p = expf(e - lmax);
      lsum += p;
      pk.u[jj] = f2bf(p);
    }
    int jc16 = qd*16 + jc;
    *reinterpret_cast<short8*>(&att[r*512 + ((jc16 ^ (r & 7)) << 3)]) = pk.v;
  }
  lsum += __shfl_xor(lsum, 1);
  lsum += __shfl_xor(lsum, 2);
  float inv_local = 1.f / lsum;
  __syncthreads();

  const int w = tid >> 6, l = tid & 63, ln = l & 15, kg = l >> 4;
  const int row = w*16 + ln;
  const u16* Bb = Wh2tbf + ((size_t)z*WW + oh*128 + ln)*DD + kg*8;
  f32x4 acc[8];
  #pragma unroll
  for (int os=0;os<8;++os) acc[os] = (f32x4){0.f,0.f,0.f,0.f};
  short8 P[8], Q[8];
  #pragma unroll
  for (int os=0; os<8; ++os) P[os] = *reinterpret_cast<const short8*>(Bb + (size_t)(os*16)*DD);
  for (int m0 = 0; m0 < 512; m0 += 64) {
    short8 a0 = *reinterpret_cast<const short8*>(&att[row*512 + ((((m0>>3)+kg) ^ (row & 7)) << 3)]);
    #pragma unroll
    for (int os=0; os<8; ++os) Q[os] = *reinterpret_cast<const short8*>(Bb + (size_t)(os*16)*DD + m0 + 32);
    #pragma unroll
    for (int os=0; os<8; ++os) acc[os] = __builtin_amdgcn_mfma_f32_16x16x32_bf16(a0, P[os], acc[os], 0,0,0);
    short8 a1 = *reinterpret_cast<const short8*>(&att[row*512 + ((((m0>>3)+4+kg) ^ (row & 7)) << 3)]);
    int nx = (m0+64 < 512) ? m0+64 : 0;
    #pragma unroll
    for (int os=0; os<8; ++os) P[os] = *reinterpret_cast<const short8*>(Bb + (size_t)(os*16)*DD + nx);
    #pragma unroll
    for (int os=0; os<8; ++os) acc[os] = __builtin_amdgcn_mfma_f32_16x16x32_bf16(a1, Q[os], acc[os], 0,0,0);
  }
  #pragma unroll
  for (int rr = 0; rr < 4; ++rr) {
    float inv = __shfl(inv_local, kg*16 + rr*4);
    int e = n0 + w*16 + kg*4 + rr;
    #pragma unroll
    for (int os = 0; os < 8; ++os) {
      float val = acc[os][rr] * inv;
      val = (val > 0.f) ? val : expm1f(val);    // elu
      g[((size_t)z*DD + e)*WW + oh*128 + os*16 + ln] = val;
    }
  }
}

// ---------- K8b: row log_softmax over o(256) -> gaty bf16 ----------
__global__ __launch_bounds__(256) void k8_lsm(
    const float* __restrict__ g, u16* __restrict__ gatybf)
{
  int row = blockIdx.x*4 + (threadIdx.x >> 6);
  int lane = threadIdx.x & 63;
  const float* gr = g + (size_t)row*WW;
  float v0 = gr[lane], v1 = gr[lane+64], v2 = gr[lane+128], v3 = gr[lane+192];
  float mx = fmaxf(fmaxf(v0,v1), fmaxf(v2,v3));
  #pragma unroll
  for (int off = 32; off >= 1; off >>= 1) mx = fmaxf(mx, __shfl_xor(mx, off));
  float sm = expf(v0-mx) + expf(v1-mx) + expf(v2-mx) + expf(v3-mx);
  #pragma unroll
  for (int off = 32; off >= 1; off >>= 1) sm += __shfl_xor(sm, off);
  float lg = mx + logf(sm);
  u16* go = gatybf + (size_t)row*WW;
  go[lane]     = f2bf(v0 - lg);
  go[lane+64]  = f2bf(v1 - lg);
  go[lane+128] = f2bf(v2 - lg);
  go[lane+192] = f2bf(v3 - lg);
}

// ---------- K9: out = gaty^T @ pW^T + pb ----------
__global__ __launch_bounds__(256) void k9_proj(
    const u16* __restrict__ gatybf, const u16* __restrict__ pWbf, const float* __restrict__ pb,
    int zb, float* __restrict__ out0)
{
  __shared__ u16 gt[64*40];
  const int t0 = blockIdx.x*64, d0 = blockIdx.y*64, z = blockIdx.z;
  const int tid = threadIdx.x;
  const int w = tid >> 6, l = tid & 63, ln = l & 15, kg = l >> 4;
  const int el = tid >> 3, t8 = tid & 7;
  f32x4 acc[4];
  #pragma unroll
  for (int os=0;os<4;++os) acc[os] = (f32x4){0.f,0.f,0.f,0.f};
  for (int e0 = 0; e0 < DD; e0 += 32) {
    __syncthreads();
    BF8 g8;
    g8.v = *reinterpret_cast<const short8*>(gatybf + ((size_t)z*DD + e0 + el)*WW + t0 + t8*8);
    #pragma unroll
    for (int j = 0; j < 8; ++j) gt[(t8*8 + j)*40 + el] = g8.u[j];
    __syncthreads();
    short8 a = *reinterpret_cast<const short8*>(&gt[(w*16 + ln)*40 + kg*8]);
    #pragma unroll
    for (int os = 0; os < 4; ++os) {
      short8 b = *reinterpret_cast<const short8*>(pWbf + (size_t)(d0 + os*16 + ln)*DD + e0 + kg*8);
      acc[os] = __builtin_amdgcn_mfma_f32_16x16x32_bf16(a, b, acc[os], 0,0,0);
    }
  }
  #pragma unroll
  for (int os=0; os<4; ++os)
    #pragma unroll
    for (int rr=0; rr<4; ++rr) {
      int t = t0 + w*16 + kg*4 + rr;
      int d = d0 + os*16 + ln;
      out0[((size_t)(zb+z)*WW + t)*DD + d] = acc[os][rr] + pb[d];
    }
}

extern "C" void kernel_launch(void* const* d_in, const int* in_sizes, int n_in,
                              void* d_out, int out_size, void* d_ws, size_t ws_size,
                              hipStream_t stream)
{
  const float* x   = (const float*)d_in[0];
  const float* qW  = (const float*)d_in[1];
  const float* qb  = (const float*)d_in[2];
  const float* kW  = (const float*)d_in[3];
  const float* kb  = (const float*)d_in[4];
  const float* vW  = (const float*)d_in[5];
  const float* vb  = (const float*)d_in[6];
  const float* hW  = (const float*)d_in[7];
  const float* hb  = (const float*)d_in[8];
  const float* hai = (const float*)d_in[9];
  const float* haib= (const float*)d_in[10];
  const float* haj = (const float*)d_in[11];
  const float* hajb= (const float*)d_in[12];
  const float* oW  = (const float*)d_in[13];
  const float* ob  = (const float*)d_in[14];
  const float* oai = (const float*)d_in[15];
  const float* oaib= (const float*)d_in[16];
  const float* oaj = (const float*)d_in[17];
  const float* oajb= (const float*)d_in[18];
  const float* pW  = (const float*)d_in[19];
  const float* pb  = (const float*)d_in[20];

  float* out0 = (float*)d_out;                   // [B,W,D] f32
  float* adjo = out0 + (size_t)BB*WW*DD;         // [B,D,D] f32

  // static region (float offsets)
  float* ws      = (float*)d_ws;
  u16*   Wt      = (u16*)(ws + 0);           // 1,179,648 f
  u16*   hWbf    = (u16*)(ws + 1179648);     //    65,536 f
  u16*   oWbf    = (u16*)(ws + 1245184);     //    65,536 f
  u16*   pWbf    = (u16*)(ws + 1310720);     //   131,072 f
  float* ahat_i  = ws + 1441792;
  float* ahat_j  = ws + 1442816;
  float* oahat_i = ws + 1443840;
  float* oahat_j = ws + 1444352;
  float* cvec    = ws + 1444864;
  float* e1h     = ws + 1444880;             //    65,536 f (CB=32 max)
  float* e2h     = ws + 1510416;
  float* e1o     = ws + 1575952;             //    16,384 f
  float* e2o     = ws + 1592336;
  const size_t X0 = 1608720;                 // dynamic region start

  // per-CB dynamic: xpad 66,048 + vbf 65,536 + qbf 65,536 + kbf 65,536 + Whtbf 131,072 = 393,728 f
  int CB = 4;
  {
    const int cand[3] = {32, 16, 8};
    for (int i = 0; i < 3; ++i) {
      size_t need = (X0 + (size_t)cand[i]*393728) * 4;
      if (need <= ws_size) { CB = cand[i]; break; }
    }
  }

  u16* xpad   = (u16*)(ws + X0);                        // CB*66,048 f  ([z][258][512])
  u16* vbf    = (u16*)(ws + X0 + (size_t)CB*66048);     // CB*65,536 f
  u16* qbf    = (u16*)(ws + X0 + (size_t)CB*131584);    // CB*65,536 f
  u16* kbf    = (u16*)(ws + X0 + (size_t)CB*197120);    // CB*65,536 f
  u16* Whtbf  = (u16*)(ws + X0 + (size_t)CB*262656);    // CB*131,072 f
  // overlays (lifetimes: xpad dead after k1; vbf dead after k4; qbf,kbf dead after k2;
  // hcatbf dead after k7; Whtbf dead after k5)
  u16*   hcatbf = (u16*)(ws + X0);                      // over xpad+vbf (CB*131,584 f >= CB*131,072)
  float* g      = (float*)(ws + X0);                    // over hcatbf region (k8 phase)
  u16*   gatybf = (u16*)(ws + X0 + (size_t)CB*131584);  // over qbf
  u16*   Wh2tbf = (u16*)(ws + X0 + (size_t)CB*197120);  // over kbf

  kprep_w<<<dim3((3*DD*DD + 255)/256), 256, 0, stream>>>(qW, kW, vW, Wt);
  kcvt<<<dim3((NHEADS*NHID*WW + 255)/256), 256, 0, stream>>>(hW, hWbf, NHEADS*NHID*WW);
  kcvt<<<dim3((WW*DD + 255)/256), 256, 0, stream>>>(oW, oWbf, WW*DD);
  kcvt<<<dim3((DD*DD + 255)/256), 256, 0, stream>>>(pW, pWbf, DD*DD);
  kprep_a<<<dim3(13), 256, 0, stream>>>(hW, hai, haib, haj, hajb, hb,
                                        oW, oai, oaib, oaj, oajb, ob,
                                        ahat_i, ahat_j, oahat_i, oahat_j, cvec);

  for (int zb = 0; zb < BB; zb += CB) {
    int nrow8 = CB*258*64;
    kprep_x  <<<dim3((nrow8 + 255)/256), 256, 0, stream>>>(x, zb, nrow8, xpad);
    k1_mfma  <<<dim3(DD/64, WW/64, CB), 256, 0, stream>>>(xpad, Wt, qb, kb, vb, qbf, kbf, vbf);
    k2_adj   <<<dim3(DD/64, DD/64, CB), 256, 0, stream>>>(qbf, kbf, zb, adjo);
    k3_wh    <<<dim3(DD/64, NHID/64, CB*NHEADS), 256, 0, stream>>>(vbf, hWbf, hb, Whtbf);
    k4_eheads<<<dim3(CB*NHEADS*DD/4), 256, 0, stream>>>(vbf, ahat_i, ahat_j, cvec, e1h, e2h);
    k5_attn  <<<dim3(DD/64, CB*NHEADS), 256, 0, stream>>>(e1h, e2h, Whtbf, hcatbf);
    k6_wh2   <<<dim3(DD/64, WW/64, CB), 256, 0, stream>>>(hcatbf, oWbf, ob, Wh2tbf);
    k7_eout  <<<dim3(CB*DD/4), 256, 0, stream>>>(hcatbf, oahat_i, oahat_j, cvec, e1o, e2o);
    k8_pv    <<<dim3(DD/64, CB, 2), 256, 0, stream>>>(e1o, e2o, Wh2tbf, g);
    k8_lsm   <<<dim3(CB*128), 256, 0, stream>>>(g, gatybf);
    k9_proj  <<<dim3(WW/64, DD/64, CB), 256, 0, stream>>>(gatybf, pWbf, pb, zb, out0);
  }
}

// Round 11
// 408.407 us; speedup vs baseline: 1.3092x; 1.1258x over previous
//
#include <hip/hip_runtime.h>
#include <math.h>

typedef unsigned short u16;
typedef __attribute__((ext_vector_type(8))) short short8;
typedef __attribute__((ext_vector_type(4))) float f32x4;

#define BB 32
#define WW 256
#define DD 512
#define NHEADS 4
#define NHID 128

__device__ __forceinline__ u16 f2bf(float f) {
  union { float f; unsigned int i; } x; x.f = f;
  unsigned int i = x.i;
  i += 0x7fffu + ((i >> 16) & 1u);
  return (u16)(i >> 16);
}
__device__ __forceinline__ float bf2f(u16 u) {
  union { float f; unsigned int i; } x; x.i = ((unsigned int)u) << 16; return x.f;
}

union BF8 { short8 v; u16 u[8]; };
union BF4 { ushort4 v; u16 u[4]; };

// ---------- prep (once) ----------
__global__ __launch_bounds__(256) void kprep_w(
    const float* __restrict__ qW, const float* __restrict__ kW, const float* __restrict__ vW,
    u16* __restrict__ Wt)
{
  int idx = blockIdx.x*256 + threadIdx.x;     // (c, o, i)
  if (idx >= 3*DD*DD) return;
  int c = idx >> 18;
  int oi = idx & (DD*DD - 1);
  int i = oi & (DD-1);
  int o = oi >> 9;
  const float* W = (c==0) ? qW : (c==1) ? kW : vW;
  float w0 = W[oi*3+0], w1 = W[oi*3+1], w2 = W[oi*3+2];
  Wt[((size_t)(c*3+0)*DD + o)*DD + i] = f2bf(w0);
  Wt[((size_t)(c*3+1)*DD + o)*DD + i] = f2bf(w1);
  Wt[((size_t)(c*3+2)*DD + o)*DD + i] = f2bf(w2);
}

__global__ __launch_bounds__(256) void kcvt(const float* __restrict__ s, u16* __restrict__ d, int n) {
  int i = blockIdx.x*256 + threadIdx.x;
  if (i < n) d[i] = f2bf(s[i]);
}

__global__ __launch_bounds__(256) void kprep_a(
    const float* __restrict__ hW, const float* __restrict__ hai, const float* __restrict__ haib,
    const float* __restrict__ haj, const float* __restrict__ hajb,
    const float* __restrict__ hb,
    const float* __restrict__ oW, const float* __restrict__ oai, const float* __restrict__ oaib,
    const float* __restrict__ oaj, const float* __restrict__ oajb,
    const float* __restrict__ ob,
    float* __restrict__ ahat_i, float* __restrict__ ahat_j,
    float* __restrict__ oahat_i, float* __restrict__ oahat_j,
    float* __restrict__ cvec)
{
  int idx = blockIdx.x*256 + threadIdx.x;
  if (idx < 1024) {
    int h = idx >> 8, f = idx & 255;
    float s = 0.f;
    for (int o = 0; o < NHID; ++o) s += hW[((size_t)h*NHID + o)*WW + f] * hai[h*NHID + o];
    ahat_i[idx] = s;
  } else if (idx < 2048) {
    int t = idx - 1024; int h = t >> 8, f = t & 255;
    float s = 0.f;
    for (int o = 0; o < NHID; ++o) s += hW[((size_t)h*NHID + o)*WW + f] * haj[h*NHID + o];
    ahat_j[t] = s;
  } else if (idx < 2560) {
    int f = idx - 2048;
    float s = 0.f;
    for (int o = 0; o < WW; ++o) s += oW[(size_t)o*DD + f] * oai[o];
    oahat_i[f] = s;
  } else if (idx < 3072) {
    int f = idx - 2560;
    float s = 0.f;
    for (int o = 0; o < WW; ++o) s += oW[(size_t)o*DD + f] * oaj[o];
    oahat_j[f] = s;
  } else if (idx < 3082) {
    int t = idx - 3072;
    if (t < 4) {
      float s = 0.f;
      for (int o = 0; o < NHID; ++o) s += hb[t*NHID + o]*hai[t*NHID + o];
      cvec[t] = s + haib[t];
    } else if (t < 8) {
      int h = t - 4; float s = 0.f;
      for (int o = 0; o < NHID; ++o) s += hb[h*NHID + o]*haj[h*NHID + o];
      cvec[t] = s + hajb[h];
    } else if (t == 8) {
      float s = 0.f;
      for (int o = 0; o < WW; ++o) s += ob[o]*oai[o];
      cvec[8] = s + oaib[0];
    } else {
      float s = 0.f;
      for (int o = 0; o < WW; ++o) s += ob[o]*oaj[o];
      cvec[9] = s + oajb[0];
    }
  }
}

// x f32 -> xpad bf16 [z][258][512] with zero halo rows (t=-1, t=256)
__global__ __launch_bounds__(256) void kprep_x(
    const float* __restrict__ x, int zb, int nrow8, u16* __restrict__ xpad)
{
  int idx8 = blockIdx.x*256 + threadIdx.x;
  if (idx8 >= nrow8) return;
  int i8 = idx8 & 63;
  int rowg = idx8 >> 6;                       // z*258 + r
  int z = rowg / 258, r = rowg - z*258;
  int t = r - 1;
  BF8 o8;
  if (t >= 0 && t < WW) {
    const float* src = x + ((size_t)(zb+z)*WW + t)*DD + i8*8;
    float4 v0 = *reinterpret_cast<const float4*>(src);
    float4 v1 = *reinterpret_cast<const float4*>(src + 4);
    o8.u[0]=f2bf(v0.x); o8.u[1]=f2bf(v0.y); o8.u[2]=f2bf(v0.z); o8.u[3]=f2bf(v0.w);
    o8.u[4]=f2bf(v1.x); o8.u[5]=f2bf(v1.y); o8.u[6]=f2bf(v1.z); o8.u[7]=f2bf(v1.w);
  } else {
    #pragma unroll
    for (int j = 0; j < 8; ++j) o8.u[j] = 0;
  }
  *reinterpret_cast<short8*>(xpad + (size_t)rowg*DD + i8*8) = o8.v;
}

// ---------- K1: conv via MFMA; B tile LDS-staged (swizzled, dbuf), A reg-prefetched ----------
__global__ __launch_bounds__(256) void k1_mfma(
    const u16* __restrict__ xpad, const u16* __restrict__ Wt,
    const float* __restrict__ qb, const float* __restrict__ kb, const float* __restrict__ vb,
    u16* __restrict__ qbf, u16* __restrict__ kbf, u16* __restrict__ vbf)
{
  __shared__ u16 bt[2][66*64];
  const int tid = threadIdx.x;
  const int w  = tid >> 6;
  const int l  = tid & 63;
  const int ln = l & 15;
  const int kg = l >> 4;
  const int og = blockIdx.x * 64 + w * 16;
  const int t0 = blockIdx.y * 64;
  const int z  = blockIdx.z;

  const u16* A0 = Wt + (size_t)(og + ln)*DD + kg*8;
  const u16* Xb = xpad + ((size_t)z*258 + t0)*DD;

  f32x4 acc[3][4];
  #pragma unroll
  for (int c=0;c<3;++c)
    #pragma unroll
    for (int ts=0;ts<4;++ts) acc[c][ts] = (f32x4){0.f,0.f,0.f,0.f};

  short8 ArP[9], ArQ[9];
  short8 sreg0, sreg1, sreg2;

  const int ccw = tid & 7;
  const int r0s = tid >> 3, r1s = (tid+256) >> 3, r2s = (tid+512) >> 3;

#define K1_LOADX(i0v) do { \
    sreg0 = *reinterpret_cast<const short8*>(Xb + (size_t)r0s*DD + (i0v) + ccw*8); \
    sreg1 = *reinterpret_cast<const short8*>(Xb + (size_t)r1s*DD + (i0v) + ccw*8); \
    if (tid < 16) sreg2 = *reinterpret_cast<const short8*>(Xb + (size_t)r2s*DD + (i0v) + ccw*8); \
  } while(0)

#define K1_WRITEX(bufv) do { \
    *reinterpret_cast<short8*>(&bt[bufv][r0s*64 + ((ccw^(r0s&7))<<3)]) = sreg0; \
    *reinterpret_cast<short8*>(&bt[bufv][r1s*64 + ((ccw^(r1s&7))<<3)]) = sreg1; \
    if (tid < 16) *reinterpret_cast<short8*>(&bt[bufv][r2s*64 + ((ccw^(r2s&7))<<3)]) = sreg2; \
  } while(0)

#define K1_LOADA(Abuf, i0v, khv) do { \
    _Pragma("unroll") \
    for (int c = 0; c < 3; ++c) { \
      _Pragma("unroll") \
      for (int tap = 0; tap < 3; ++tap) \
        Abuf[c*3+tap] = *reinterpret_cast<const short8*>(A0 + (size_t)(c*3+tap)*DD*DD + (i0v) + (khv)*32); \
    } \
  } while(0)

#define K1_MFMAS(Abuf, khv) do { \
    _Pragma("unroll") \
    for (int tap = 0; tap < 3; ++tap) { \
      _Pragma("unroll") \
      for (int ts = 0; ts < 4; ++ts) { \
        int row = ts*16 + ln + tap; \
        short8 bfr = *reinterpret_cast<const short8*>(&bt[cur][row*64 + ((((khv)*4+kg) ^ (row&7))<<3)]); \
        acc[0][ts] = __builtin_amdgcn_mfma_f32_16x16x32_bf16(Abuf[0*3+tap], bfr, acc[0][ts], 0,0,0); \
        acc[1][ts] = __builtin_amdgcn_mfma_f32_16x16x32_bf16(Abuf[1*3+tap], bfr, acc[1][ts], 0,0,0); \
        acc[2][ts] = __builtin_amdgcn_mfma_f32_16x16x32_bf16(Abuf[2*3+tap], bfr, acc[2][ts], 0,0,0); \
      } \
    } \
  } while(0)

  K1_LOADX(0);
  K1_LOADA(ArP, 0, 0);
  K1_WRITEX(0);
  __syncthreads();

  int cur = 0;
  #pragma unroll 1
  for (int p = 0; p < 8; ++p) {
    const int i0 = p*64;
    if (p < 7) K1_LOADX(i0 + 64);
    K1_LOADA(ArQ, i0, 1);
    K1_MFMAS(ArP, 0);
    const int i0n = (p < 7) ? i0 + 64 : 0;
    K1_LOADA(ArP, i0n, 0);
    K1_MFMAS(ArQ, 1);
    if (p < 7) {
      K1_WRITEX(cur ^ 1);
      __syncthreads();
      cur ^= 1;
    }
  }

#undef K1_LOADX
#undef K1_WRITEX
#undef K1_LOADA
#undef K1_MFMAS

  #pragma unroll
  for (int ts=0; ts<4; ++ts) {
    int tg = t0 + ts*16 + ln;
    #pragma unroll
    for (int r=0;r<4;++r) {
      int o = og + kg*4 + r;
      size_t oi = (size_t)(z*DD + o)*WW + tg;
      qbf[oi] = f2bf(acc[0][ts][r] + qb[o]);
      kbf[oi] = f2bf(acc[1][ts][r] + kb[o]);
      vbf[oi] = f2bf(acc[2][ts][r] + vb[o]);
    }
  }
}

// ---------- K2: adj = sigmoid(q.kT * scale) ----------
__global__ __launch_bounds__(256) void k2_adj(
    const u16* __restrict__ qbf, const u16* __restrict__ kbf, int zb, float* __restrict__ adjo)
{
  const int w = threadIdx.x >> 6, l = threadIdx.x & 63;
  const int ln = l & 15, kg = l >> 4;
  const int d0 = blockIdx.x*64 + w*16;
  const int e0 = blockIdx.y*64;
  const int z  = blockIdx.z;
  f32x4 acc[4];
  #pragma unroll
  for (int es=0;es<4;++es) acc[es] = (f32x4){0.f,0.f,0.f,0.f};
  for (int t0 = 0; t0 < WW; t0 += 32) {
    short8 a = *reinterpret_cast<const short8*>(qbf + ((size_t)(z*DD + d0 + ln)*WW + t0 + kg*8));
    #pragma unroll
    for (int es=0; es<4; ++es) {
      short8 b = *reinterpret_cast<const short8*>(kbf + ((size_t)(z*DD + e0 + es*16 + ln)*WW + t0 + kg*8));
      acc[es] = __builtin_amdgcn_mfma_f32_16x16x32_bf16(a, b, acc[es], 0,0,0);
    }
  }
  const float scale = 0.044194173824159216f;
  #pragma unroll
  for (int es=0; es<4; ++es)
    #pragma unroll
    for (int r=0; r<4; ++r) {
      float sig = 1.f/(1.f + expf(-acc[es][r]*scale));
      adjo[((size_t)(zb+z)*DD + d0 + kg*4 + r)*DD + e0 + es*16 + ln] = sig;
    }
}

// ---------- K3: Whtbf[zh][o][n] = (v @ hW^T + hb)^T bf16 ----------
__global__ __launch_bounds__(256) void k3_wh(
    const u16* __restrict__ vbf, const u16* __restrict__ hWbf, const float* __restrict__ hb,
    u16* __restrict__ Whtbf)
{
  const int w = threadIdx.x >> 6, l = threadIdx.x & 63;
  const int ln = l & 15, kg = l >> 4;
  const int n0 = blockIdx.x*64 + w*16;
  const int o0 = blockIdx.y*64;
  const int zh = blockIdx.z, z = zh >> 2, h = zh & 3;
  f32x4 acc[4];
  #pragma unroll
  for (int os=0;os<4;++os) acc[os] = (f32x4){0.f,0.f,0.f,0.f};
  for (int f0 = 0; f0 < WW; f0 += 32) {
    short8 a = *reinterpret_cast<const short8*>(vbf + ((size_t)(z*DD + n0 + ln)*WW + f0 + kg*8));
    #pragma unroll
    for (int os=0; os<4; ++os) {
      short8 b = *reinterpret_cast<const short8*>(hWbf + ((size_t)(h*NHID + o0 + os*16 + ln)*WW + f0 + kg*8));
      acc[os] = __builtin_amdgcn_mfma_f32_16x16x32_bf16(a, b, acc[os], 0,0,0);
    }
  }
  #pragma unroll
  for (int os=0; os<4; ++os)
    #pragma unroll
    for (int r=0; r<4; ++r) {
      int o = o0 + os*16 + ln;
      int n = n0 + kg*4 + r;
      Whtbf[((size_t)zh*NHID + o)*DD + n] = f2bf(acc[os][r] + hb[h*NHID + o]);
    }
}

// ---------- K4: e1h/e2h ----------
__global__ __launch_bounds__(256) void k4_eheads(
    const u16* __restrict__ vbf,
    const float* __restrict__ ahat_i, const float* __restrict__ ahat_j,
    const float* __restrict__ cvec,
    float* __restrict__ e1, float* __restrict__ e2)
{
  int row = blockIdx.x*4 + (threadIdx.x >> 6);   // row = zh*512 + n
  int lane = threadIdx.x & 63;
  int zh = row >> 9, n = row & 511;
  int z = zh >> 2, h = zh & 3;
  BF4 v4; v4.v = *reinterpret_cast<const ushort4*>(vbf + ((size_t)(z*DD + n))*WW + lane*4);
  const float* aif = ahat_i + h*WW + lane*4;
  const float* ajf = ahat_j + h*WW + lane*4;
  float a1 = 0.f, a2 = 0.f;
  #pragma unroll
  for (int j = 0; j < 4; ++j) {
    float vf = bf2f(v4.u[j]);
    a1 += vf * aif[j];
    a2 += vf * ajf[j];
  }
  #pragma unroll
  for (int off = 32; off >= 1; off >>= 1) { a1 += __shfl_xor(a1, off); a2 += __shfl_xor(a2, off); }
  if (lane == 0) { e1[row] = a1 + cvec[h]; e2[row] = a2 + cvec[4+h]; }
}

// swizzled att chunk index: bijective, spreads chunk bits 3..5 into bank group
__device__ __forceinline__ int attsw(int c, int row) {
  return c ^ ((c >> 3) & 7) ^ (row & 7);
}

// ---------- K5: heads attention; os-split waves, depth-3 B prefetch ----------
__global__ __launch_bounds__(256) void k5_attn(
    const float* __restrict__ e1h, const float* __restrict__ e2h,
    const u16* __restrict__ Whtbf, u16* __restrict__ hcatbf)
{
  __shared__ u16 att[64*512];
  __shared__ float inv_lds[64];
  const int nb = blockIdx.x, zh = blockIdx.y;
  const int z = zh >> 2, h = zh & 3;
  const int n0 = nb*64;
  const int tid = threadIdx.x;

  // phase A: softmax numerators (unnormalized bf16) into swizzled att
  const int r = tid >> 2, qd = tid & 3;
  const float e1n = e1h[(size_t)zh*DD + n0 + r];
  const float* e2r = e2h + (size_t)zh*DD + qd*128;
  float lmax = -1e30f;
  for (int j = 0; j < 128; ++j) {
    float e = e1n + e2r[j];
    e = (e > 0.f) ? e : 0.1f*e;
    lmax = fmaxf(lmax, e);
  }
  lmax = fmaxf(lmax, __shfl_xor(lmax, 1));
  lmax = fmaxf(lmax, __shfl_xor(lmax, 2));
  float lsum = 0.f;
  for (int jc = 0; jc < 16; ++jc) {
    BF8 pk;
    #pragma unroll
    for (int jj = 0; jj < 8; ++jj) {
      float e = e1n + e2r[jc*8 + jj];
      e = (e > 0.f) ? e : 0.1f*e;
      float p = expf(e - lmax);
      lsum += p;
      pk.u[jj] = f2bf(p);
    }
    int c = qd*16 + jc;
    *reinterpret_cast<short8*>(&att[r*512 + attsw(c, r)*8]) = pk.v;
  }
  lsum += __shfl_xor(lsum, 1);
  lsum += __shfl_xor(lsum, 2);
  if ((tid & 3) == 0) inv_lds[r] = 1.f / lsum;
  __syncthreads();

  // phase B: PV. wave w owns os {2w, 2w+1}; all 64 n rows.
  const int w = tid >> 6, l = tid & 63, ln = l & 15, kg = l >> 4;
  const u16* B0 = Whtbf + ((size_t)zh*NHID + w*32 + ln)*DD + kg*8;
  f32x4 acc[4][2];
  #pragma unroll
  for (int ns=0; ns<4; ++ns) { acc[ns][0] = (f32x4){0,0,0,0}; acc[ns][1] = (f32x4){0,0,0,0}; }

  short8 Pb0,Pb1,Qb0,Qb1,Rb0,Rb1,Sb0,Sb1;
#define K5_LDB(R0,R1,kkv) do { int kc = ((kkv) < 16) ? (kkv) : 0; \
    R0 = *reinterpret_cast<const short8*>(B0 + (size_t)kc*32); \
    R1 = *reinterpret_cast<const short8*>(B0 + (size_t)16*DD + (size_t)kc*32); } while(0)
#define K5_MM(R0,R1,kkv) do { \
    _Pragma("unroll") \
    for (int ns = 0; ns < 4; ++ns) { \
      int row = ns*16 + ln; int c = (kkv)*4 + kg; \
      short8 af = *reinterpret_cast<const short8*>(&att[row*512 + attsw(c,row)*8]); \
      acc[ns][0] = __builtin_amdgcn_mfma_f32_16x16x32_bf16(af, R0, acc[ns][0], 0,0,0); \
      acc[ns][1] = __builtin_amdgcn_mfma_f32_16x16x32_bf16(af, R1, acc[ns][1], 0,0,0); \
    } } while(0)

  K5_LDB(Pb0,Pb1,0); K5_LDB(Qb0,Qb1,1); K5_LDB(Rb0,Rb1,2);
  #pragma unroll 1
  for (int kk = 0; kk < 16; kk += 4) {
    K5_LDB(Sb0,Sb1,kk+3); K5_MM(Pb0,Pb1,kk);
    K5_LDB(Pb0,Pb1,kk+4); K5_MM(Qb0,Qb1,kk+1);
    K5_LDB(Qb0,Qb1,kk+5); K5_MM(Rb0,Rb1,kk+2);
    K5_LDB(Rb0,Rb1,kk+6); K5_MM(Sb0,Sb1,kk+3);
  }
#undef K5_LDB
#undef K5_MM

  #pragma unroll
  for (int ns = 0; ns < 4; ++ns)
    #pragma unroll
    for (int rr = 0; rr < 4; ++rr) {
      int n = ns*16 + kg*4 + rr;
      float inv = inv_lds[n];
      #pragma unroll
      for (int j = 0; j < 2; ++j) {
        float s = acc[ns][j][rr] * inv;
        s = (s > 0.f) ? s : expm1f(s);
        hcatbf[((size_t)z*DD + n0 + n)*DD + h*NHID + w*32 + j*16 + ln] = f2bf(s);
      }
    }
}

// ---------- K6: Wh2tbf[z][o][n] bf16 ----------
__global__ __launch_bounds__(256) void k6_wh2(
    const u16* __restrict__ hcatbf, const u16* __restrict__ oWbf, const float* __restrict__ ob,
    u16* __restrict__ Wh2tbf)
{
  const int w = threadIdx.x >> 6, l = threadIdx.x & 63;
  const int ln = l & 15, kg = l >> 4;
  const int n0 = blockIdx.x*64 + w*16;
  const int o0 = blockIdx.y*64;
  const int z  = blockIdx.z;
  f32x4 acc[4];
  #pragma unroll
  for (int os=0;os<4;++os) acc[os] = (f32x4){0.f,0.f,0.f,0.f};
  for (int f0 = 0; f0 < DD; f0 += 32) {
    short8 a = *reinterpret_cast<const short8*>(hcatbf + ((size_t)(z*DD + n0 + ln))*DD + f0 + kg*8);
    #pragma unroll
    for (int os=0; os<4; ++os) {
      short8 b = *reinterpret_cast<const short8*>(oWbf + (size_t)(o0 + os*16 + ln)*DD + f0 + kg*8);
      acc[os] = __builtin_amdgcn_mfma_f32_16x16x32_bf16(a, b, acc[os], 0,0,0);
    }
  }
  #pragma unroll
  for (int os=0; os<4; ++os)
    #pragma unroll
    for (int r=0; r<4; ++r) {
      int o = o0 + os*16 + ln;
      int n = n0 + kg*4 + r;
      Wh2tbf[((size_t)z*WW + o)*DD + n] = f2bf(acc[os][r] + ob[o]);
    }
}

// ---------- K7: e1o/e2o ----------
__global__ __launch_bounds__(256) void k7_eout(
    const u16* __restrict__ hcatbf,
    const float* __restrict__ oahat_i, const float* __restrict__ oahat_j,
    const float* __restrict__ cvec,
    float* __restrict__ e1, float* __restrict__ e2)
{
  int row = blockIdx.x*4 + (threadIdx.x >> 6);
  int lane = threadIdx.x & 63;
  BF8 v8; v8.v = *reinterpret_cast<const short8*>(hcatbf + (size_t)row*DD + lane*8);
  float a1 = 0.f, a2 = 0.f;
  #pragma unroll
  for (int j = 0; j < 8; ++j) {
    float vf = bf2f(v8.u[j]);
    a1 += vf * oahat_i[lane*8 + j];
    a2 += vf * oahat_j[lane*8 + j];
  }
  #pragma unroll
  for (int off = 32; off >= 1; off >>= 1) { a1 += __shfl_xor(a1, off); a2 += __shfl_xor(a2, off); }
  if (lane == 0) { e1[row] = a1 + cvec[8]; e2[row] = a2 + cvec[9]; }
}

// ---------- K8a: out attention PV; os-split waves, depth-3 prefetch -> g f32 (elu) ----------
__global__ __launch_bounds__(256) void k8_pv(
    const float* __restrict__ e1o, const float* __restrict__ e2o,
    const u16* __restrict__ Wh2tbf, float* __restrict__ g)
{
  __shared__ u16 att[64*512];
  __shared__ float inv_lds[64];
  const int nb = blockIdx.x, z = blockIdx.y, oh = blockIdx.z;
  const int n0 = nb*64;
  const int tid = threadIdx.x;

  const int r = tid >> 2, qd = tid & 3;
  const float e1n = e1o[(size_t)z*DD + n0 + r];
  const float* e2r = e2o + (size_t)z*DD + qd*128;
  float lmax = -1e30f;
  for (int j = 0; j < 128; ++j) {
    float e = e1n + e2r[j];
    e = (e > 0.f) ? e : 0.1f*e;
    lmax = fmaxf(lmax, e);
  }
  lmax = fmaxf(lmax, __shfl_xor(lmax, 1));
  lmax = fmaxf(lmax, __shfl_xor(lmax, 2));
  float lsum = 0.f;
  for (int jc = 0; jc < 16; ++jc) {
    BF8 pk;
    #pragma unroll
    for (int jj = 0; jj < 8; ++jj) {
      float e = e1n + e2r[jc*8 + jj];
      e = (e > 0.f) ? e : 0.1f*e;
      float p = expf(e - lmax);
      lsum += p;
      pk.u[jj] = f2bf(p);
    }
    int c = qd*16 + jc;
    *reinterpret_cast<short8*>(&att[r*512 + attsw(c, r)*8]) = pk.v;
  }
  lsum += __shfl_xor(lsum, 1);
  lsum += __shfl_xor(lsum, 2);
  if ((tid & 3) == 0) inv_lds[r] = 1.f / lsum;
  __syncthreads();

  const int w = tid >> 6, l = tid & 63, ln = l & 15, kg = l >> 4;
  const u16* B0 = Wh2tbf + ((size_t)z*WW + oh*128 + w*32 + ln)*DD + kg*8;
  f32x4 acc[4][2];
  #pragma unroll
  for (int ns=0; ns<4; ++ns) { acc[ns][0] = (f32x4){0,0,0,0}; acc[ns][1] = (f32x4){0,0,0,0}; }

  short8 Pb0,Pb1,Qb0,Qb1,Rb0,Rb1,Sb0,Sb1;
#define K8_LDB(R0,R1,kkv) do { int kc = ((kkv) < 16) ? (kkv) : 0; \
    R0 = *reinterpret_cast<const short8*>(B0 + (size_t)kc*32); \
    R1 = *reinterpret_cast<const short8*>(B0 + (size_t)16*DD + (size_t)kc*32); } while(0)
#define K8_MM(R0,R1,kkv) do { \
    _Pragma("unroll") \
    for (int ns = 0; ns < 4; ++ns) { \
      int row = ns*16 + ln; int c = (kkv)*4 + kg; \
      short8 af = *reinterpret_cast<const short8*>(&att[row*512 + attsw(c,row)*8]); \
      acc[ns][0] = __builtin_amdgcn_mfma_f32_16x16x32_bf16(af, R0, acc[ns][0], 0,0,0); \
      acc[ns][1] = __builtin_amdgcn_mfma_f32_16x16x32_bf16(af, R1, acc[ns][1], 0,0,0); \
    } } while(0)

  K8_LDB(Pb0,Pb1,0); K8_LDB(Qb0,Qb1,1); K8_LDB(Rb0,Rb1,2);
  #pragma unroll 1
  for (int kk = 0; kk < 16; kk += 4) {
    K8_LDB(Sb0,Sb1,kk+3); K8_MM(Pb0,Pb1,kk);
    K8_LDB(Pb0,Pb1,kk+4); K8_MM(Qb0,Qb1,kk+1);
    K8_LDB(Qb0,Qb1,kk+5); K8_MM(Rb0,Rb1,kk+2);
    K8_LDB(Rb0,Rb1,kk+6); K8_MM(Sb0,Sb1,kk+3);
  }
#undef K8_LDB
#undef K8_MM

  #pragma unroll
  for (int ns = 0; ns < 4; ++ns)
    #pragma unroll
    for (int rr = 0; rr < 4; ++rr) {
      int n = ns*16 + kg*4 + rr;
      float inv = inv_lds[n];
      #pragma unroll
      for (int j = 0; j < 2; ++j) {
        float val = acc[ns][j][rr] * inv;
        val = (val > 0.f) ? val : expm1f(val);    // elu
        g[((size_t)z*DD + n0 + n)*WW + oh*128 + w*32 + j*16 + ln] = val;
      }
    }
}

// ---------- K8b: row log_softmax over o(256) -> gaty bf16 ----------
__global__ __launch_bounds__(256) void k8_lsm(
    const float* __restrict__ g, u16* __restrict__ gatybf)
{
  int row = blockIdx.x*4 + (threadIdx.x >> 6);
  int lane = threadIdx.x & 63;
  const float* gr = g + (size_t)row*WW;
  float v0 = gr[lane], v1 = gr[lane+64], v2 = gr[lane+128], v3 = gr[lane+192];
  float mx = fmaxf(fmaxf(v0,v1), fmaxf(v2,v3));
  #pragma unroll
  for (int off = 32; off >= 1; off >>= 1) mx = fmaxf(mx, __shfl_xor(mx, off));
  float sm = expf(v0-mx) + expf(v1-mx) + expf(v2-mx) + expf(v3-mx);
  #pragma unroll
  for (int off = 32; off >= 1; off >>= 1) sm += __shfl_xor(sm, off);
  float lg = mx + logf(sm);
  u16* go = gatybf + (size_t)row*WW;
  go[lane]     = f2bf(v0 - lg);
  go[lane+64]  = f2bf(v1 - lg);
  go[lane+128] = f2bf(v2 - lg);
  go[lane+192] = f2bf(v3 - lg);
}

// ---------- K9: out = gaty^T @ pW^T + pb ----------
__global__ __launch_bounds__(256) void k9_proj(
    const u16* __restrict__ gatybf, const u16* __restrict__ pWbf, const float* __restrict__ pb,
    int zb, float* __restrict__ out0)
{
  __shared__ u16 gt[64*40];
  const int t0 = blockIdx.x*64, d0 = blockIdx.y*64, z = blockIdx.z;
  const int tid = threadIdx.x;
  const int w = tid >> 6, l = tid & 63, ln = l & 15, kg = l >> 4;
  const int el = tid >> 3, t8 = tid & 7;
  f32x4 acc[4];
  #pragma unroll
  for (int os=0;os<4;++os) acc[os] = (f32x4){0.f,0.f,0.f,0.f};
  for (int e0 = 0; e0 < DD; e0 += 32) {
    __syncthreads();
    BF8 g8;
    g8.v = *reinterpret_cast<const short8*>(gatybf + ((size_t)z*DD + e0 + el)*WW + t0 + t8*8);
    #pragma unroll
    for (int j = 0; j < 8; ++j) gt[(t8*8 + j)*40 + el] = g8.u[j];
    __syncthreads();
    short8 a = *reinterpret_cast<const short8*>(&gt[(w*16 + ln)*40 + kg*8]);
    #pragma unroll
    for (int os = 0; os < 4; ++os) {
      short8 b = *reinterpret_cast<const short8*>(pWbf + (size_t)(d0 + os*16 + ln)*DD + e0 + kg*8);
      acc[os] = __builtin_amdgcn_mfma_f32_16x16x32_bf16(a, b, acc[os], 0,0,0);
    }
  }
  #pragma unroll
  for (int os=0; os<4; ++os)
    #pragma unroll
    for (int rr=0; rr<4; ++rr) {
      int t = t0 + w*16 + kg*4 + rr;
      int d = d0 + os*16 + ln;
      out0[((size_t)(zb+z)*WW + t)*DD + d] = acc[os][rr] + pb[d];
    }
}

extern "C" void kernel_launch(void* const* d_in, const int* in_sizes, int n_in,
                              void* d_out, int out_size, void* d_ws, size_t ws_size,
                              hipStream_t stream)
{
  const float* x   = (const float*)d_in[0];
  const float* qW  = (const float*)d_in[1];
  const float* qb  = (const float*)d_in[2];
  const float* kW  = (const float*)d_in[3];
  const float* kb  = (const float*)d_in[4];
  const float* vW  = (const float*)d_in[5];
  const float* vb  = (const float*)d_in[6];
  const float* hW  = (const float*)d_in[7];
  const float* hb  = (const float*)d_in[8];
  const float* hai = (const float*)d_in[9];
  const float* haib= (const float*)d_in[10];
  const float* haj = (const float*)d_in[11];
  const float* hajb= (const float*)d_in[12];
  const float* oW  = (const float*)d_in[13];
  const float* ob  = (const float*)d_in[14];
  const float* oai = (const float*)d_in[15];
  const float* oaib= (const float*)d_in[16];
  const float* oaj = (const float*)d_in[17];
  const float* oajb= (const float*)d_in[18];
  const float* pW  = (const float*)d_in[19];
  const float* pb  = (const float*)d_in[20];

  float* out0 = (float*)d_out;                   // [B,W,D] f32
  float* adjo = out0 + (size_t)BB*WW*DD;         // [B,D,D] f32

  // static region (float offsets)
  float* ws      = (float*)d_ws;
  u16*   Wt      = (u16*)(ws + 0);           // 1,179,648 f
  u16*   hWbf    = (u16*)(ws + 1179648);     //    65,536 f
  u16*   oWbf    = (u16*)(ws + 1245184);     //    65,536 f
  u16*   pWbf    = (u16*)(ws + 1310720);     //   131,072 f
  float* ahat_i  = ws + 1441792;
  float* ahat_j  = ws + 1442816;
  float* oahat_i = ws + 1443840;
  float* oahat_j = ws + 1444352;
  float* cvec    = ws + 1444864;
  float* e1h     = ws + 1444880;             //    65,536 f (CB=32 max)
  float* e2h     = ws + 1510416;
  float* e1o     = ws + 1575952;             //    16,384 f
  float* e2o     = ws + 1592336;
  const size_t X0 = 1608720;                 // dynamic region start

  // per-CB dynamic: xpad 66,048 + vbf 65,536 + qbf 65,536 + kbf 65,536 + Whtbf 131,072 = 393,728 f
  int CB = 4;
  {
    const int cand[3] = {32, 16, 8};
    for (int i = 0; i < 3; ++i) {
      size_t need = (X0 + (size_t)cand[i]*393728) * 4;
      if (need <= ws_size) { CB = cand[i]; break; }
    }
  }

  u16* xpad   = (u16*)(ws + X0);                        // CB*66,048 f  ([z][258][512])
  u16* vbf    = (u16*)(ws + X0 + (size_t)CB*66048);     // CB*65,536 f
  u16* qbf    = (u16*)(ws + X0 + (size_t)CB*131584);    // CB*65,536 f
  u16* kbf    = (u16*)(ws + X0 + (size_t)CB*197120);    // CB*65,536 f
  u16* Whtbf  = (u16*)(ws + X0 + (size_t)CB*262656);    // CB*131,072 f
  // overlays (lifetimes: xpad dead after k1; vbf dead after k4; qbf,kbf dead after k2;
  // hcatbf dead after k7; Whtbf dead after k5)
  u16*   hcatbf = (u16*)(ws + X0);                      // over xpad+vbf
  float* g      = (float*)(ws + X0);                    // over hcatbf region (k8 phase)
  u16*   gatybf = (u16*)(ws + X0 + (size_t)CB*131584);  // over qbf
  u16*   Wh2tbf = (u16*)(ws + X0 + (size_t)CB*197120);  // over kbf

  kprep_w<<<dim3((3*DD*DD + 255)/256), 256, 0, stream>>>(qW, kW, vW, Wt);
  kcvt<<<dim3((NHEADS*NHID*WW + 255)/256), 256, 0, stream>>>(hW, hWbf, NHEADS*NHID*WW);
  kcvt<<<dim3((WW*DD + 255)/256), 256, 0, stream>>>(oW, oWbf, WW*DD);
  kcvt<<<dim3((DD*DD + 255)/256), 256, 0, stream>>>(pW, pWbf, DD*DD);
  kprep_a<<<dim3(13), 256, 0, stream>>>(hW, hai, haib, haj, hajb, hb,
                                        oW, oai, oaib, oaj, oajb, ob,
                                        ahat_i, ahat_j, oahat_i, oahat_j, cvec);

  for (int zb = 0; zb < BB; zb += CB) {
    int nrow8 = CB*258*64;
    kprep_x  <<<dim3((nrow8 + 255)/256), 256, 0, stream>>>(x, zb, nrow8, xpad);
    k1_mfma  <<<dim3(DD/64, WW/64, CB), 256, 0, stream>>>(xpad, Wt, qb, kb, vb, qbf, kbf, vbf);
    k2_adj   <<<dim3(DD/64, DD/64, CB), 256, 0, stream>>>(qbf, kbf, zb, adjo);
    k3_wh    <<<dim3(DD/64, NHID/64, CB*NHEADS), 256, 0, stream>>>(vbf, hWbf, hb, Whtbf);
    k4_eheads<<<dim3(CB*NHEADS*DD/4), 256, 0, stream>>>(vbf, ahat_i, ahat_j, cvec, e1h, e2h);
    k5_attn  <<<dim3(DD/64, CB*NHEADS), 256, 0, stream>>>(e1h, e2h, Whtbf, hcatbf);
    k6_wh2   <<<dim3(DD/64, WW/64, CB), 256, 0, stream>>>(hcatbf, oWbf, ob, Wh2tbf);
    k7_eout  <<<dim3(CB*DD/4), 256, 0, stream>>>(hcatbf, oahat_i, oahat_j, cvec, e1o, e2o);
    k8_pv    <<<dim3(DD/64, CB, 2), 256, 0, stream>>>(e1o, e2o, Wh2tbf, g);
    k8_lsm   <<<dim3(CB*128), 256, 0, stream>>>(g, gatybf);
    k9_proj  <<<dim3(WW/64, DD/64, CB), 256, 0, stream>>>(gatybf, pWbf, pb, zb, out0);
  }
}

// Round 12
// 344.245 us; speedup vs baseline: 1.5532x; 1.1864x over previous
//
#include <hip/hip_runtime.h>
#include <math.h>

typedef unsigned short u16;
typedef __attribute__((ext_vector_type(8))) short short8;
typedef __attribute__((ext_vector_type(4))) float f32x4;

#define BB 32
#define WW 256
#define DD 512
#define NHEADS 4
#define NHID 128

__device__ __forceinline__ u16 f2bf(float f) {
  union { float f; unsigned int i; } x; x.f = f;
  unsigned int i = x.i;
  i += 0x7fffu + ((i >> 16) & 1u);
  return (u16)(i >> 16);
}
__device__ __forceinline__ float bf2f(u16 u) {
  union { float f; unsigned int i; } x; x.i = ((unsigned int)u) << 16; return x.f;
}

union BF8 { short8 v; u16 u[8]; };
union BF4 { ushort4 v; u16 u[4]; };

// ---------- prep (once) ----------
__global__ __launch_bounds__(256) void kprep_w(
    const float* __restrict__ qW, const float* __restrict__ kW, const float* __restrict__ vW,
    u16* __restrict__ Wt)
{
  int idx = blockIdx.x*256 + threadIdx.x;     // (c, o, i)
  if (idx >= 3*DD*DD) return;
  int c = idx >> 18;
  int oi = idx & (DD*DD - 1);
  int i = oi & (DD-1);
  int o = oi >> 9;
  const float* W = (c==0) ? qW : (c==1) ? kW : vW;
  float w0 = W[oi*3+0], w1 = W[oi*3+1], w2 = W[oi*3+2];
  Wt[((size_t)(c*3+0)*DD + o)*DD + i] = f2bf(w0);
  Wt[((size_t)(c*3+1)*DD + o)*DD + i] = f2bf(w1);
  Wt[((size_t)(c*3+2)*DD + o)*DD + i] = f2bf(w2);
}

__global__ __launch_bounds__(256) void kcvt(const float* __restrict__ s, u16* __restrict__ d, int n) {
  int i = blockIdx.x*256 + threadIdx.x;
  if (i < n) d[i] = f2bf(s[i]);
}

__global__ __launch_bounds__(256) void kprep_a(
    const float* __restrict__ hW, const float* __restrict__ hai, const float* __restrict__ haib,
    const float* __restrict__ haj, const float* __restrict__ hajb,
    const float* __restrict__ hb,
    const float* __restrict__ oW, const float* __restrict__ oai, const float* __restrict__ oaib,
    const float* __restrict__ oaj, const float* __restrict__ oajb,
    const float* __restrict__ ob,
    float* __restrict__ ahat_i, float* __restrict__ ahat_j,
    float* __restrict__ oahat_i, float* __restrict__ oahat_j,
    float* __restrict__ cvec)
{
  int idx = blockIdx.x*256 + threadIdx.x;
  if (idx < 1024) {
    int h = idx >> 8, f = idx & 255;
    float s = 0.f;
    for (int o = 0; o < NHID; ++o) s += hW[((size_t)h*NHID + o)*WW + f] * hai[h*NHID + o];
    ahat_i[idx] = s;
  } else if (idx < 2048) {
    int t = idx - 1024; int h = t >> 8, f = t & 255;
    float s = 0.f;
    for (int o = 0; o < NHID; ++o) s += hW[((size_t)h*NHID + o)*WW + f] * haj[h*NHID + o];
    ahat_j[t] = s;
  } else if (idx < 2560) {
    int f = idx - 2048;
    float s = 0.f;
    for (int o = 0; o < WW; ++o) s += oW[(size_t)o*DD + f] * oai[o];
    oahat_i[f] = s;
  } else if (idx < 3072) {
    int f = idx - 2560;
    float s = 0.f;
    for (int o = 0; o < WW; ++o) s += oW[(size_t)o*DD + f] * oaj[o];
    oahat_j[f] = s;
  } else if (idx < 3082) {
    int t = idx - 3072;
    if (t < 4) {
      float s = 0.f;
      for (int o = 0; o < NHID; ++o) s += hb[t*NHID + o]*hai[t*NHID + o];
      cvec[t] = s + haib[t];
    } else if (t < 8) {
      int h = t - 4; float s = 0.f;
      for (int o = 0; o < NHID; ++o) s += hb[h*NHID + o]*haj[h*NHID + o];
      cvec[t] = s + hajb[h];
    } else if (t == 8) {
      float s = 0.f;
      for (int o = 0; o < WW; ++o) s += ob[o]*oai[o];
      cvec[8] = s + oaib[0];
    } else {
      float s = 0.f;
      for (int o = 0; o < WW; ++o) s += ob[o]*oaj[o];
      cvec[9] = s + oajb[0];
    }
  }
}

// x f32 -> xpad bf16 [z][258][512] with zero halo rows (t=-1, t=256)
__global__ __launch_bounds__(256) void kprep_x(
    const float* __restrict__ x, int zb, int nrow8, u16* __restrict__ xpad)
{
  int idx8 = blockIdx.x*256 + threadIdx.x;
  if (idx8 >= nrow8) return;
  int i8 = idx8 & 63;
  int rowg = idx8 >> 6;                       // z*258 + r
  int z = rowg / 258, r = rowg - z*258;
  int t = r - 1;
  BF8 o8;
  if (t >= 0 && t < WW) {
    const float* src = x + ((size_t)(zb+z)*WW + t)*DD + i8*8;
    float4 v0 = *reinterpret_cast<const float4*>(src);
    float4 v1 = *reinterpret_cast<const float4*>(src + 4);
    o8.u[0]=f2bf(v0.x); o8.u[1]=f2bf(v0.y); o8.u[2]=f2bf(v0.z); o8.u[3]=f2bf(v0.w);
    o8.u[4]=f2bf(v1.x); o8.u[5]=f2bf(v1.y); o8.u[6]=f2bf(v1.z); o8.u[7]=f2bf(v1.w);
  } else {
    #pragma unroll
    for (int j = 0; j < 8; ++j) o8.u[j] = 0;
  }
  *reinterpret_cast<short8*>(xpad + (size_t)rowg*DD + i8*8) = o8.v;
}

// ---------- K1: conv via MFMA; B LDS-staged; XCD-affine 1-D grid ----------
// grid = 32*CB blocks * 8: id = ogrp + 8*(tgrp + 4*z) -> xcd(id)=id%8=ogrp:
// all blocks sharing an o-panel land on one XCD (A-slice stays L2-hot).
__global__ __launch_bounds__(256) void k1_mfma(
    const u16* __restrict__ xpad, const u16* __restrict__ Wt,
    const float* __restrict__ qb, const float* __restrict__ kb, const float* __restrict__ vb,
    u16* __restrict__ qbf, u16* __restrict__ kbf, u16* __restrict__ vbf)
{
  __shared__ u16 bt[2][66*64];
  const int tid = threadIdx.x;
  const int id = blockIdx.x;
  const int bx = id & 7;
  const int j  = id >> 3;
  const int by = j & 3;
  const int z  = j >> 2;
  const int w  = tid >> 6;
  const int l  = tid & 63;
  const int ln = l & 15;
  const int kg = l >> 4;
  const int og = bx * 64 + w * 16;
  const int t0 = by * 64;

  const u16* A0 = Wt + (size_t)(og + ln)*DD + kg*8;
  const u16* Xb = xpad + ((size_t)z*258 + t0)*DD;

  f32x4 acc[3][4];
  #pragma unroll
  for (int c=0;c<3;++c)
    #pragma unroll
    for (int ts=0;ts<4;++ts) acc[c][ts] = (f32x4){0.f,0.f,0.f,0.f};

  short8 ArP[9], ArQ[9];
  short8 sreg0, sreg1, sreg2;

  const int ccw = tid & 7;
  const int r0s = tid >> 3, r1s = (tid+256) >> 3, r2s = (tid+512) >> 3;

#define K1_LOADX(i0v) do { \
    sreg0 = *reinterpret_cast<const short8*>(Xb + (size_t)r0s*DD + (i0v) + ccw*8); \
    sreg1 = *reinterpret_cast<const short8*>(Xb + (size_t)r1s*DD + (i0v) + ccw*8); \
    if (tid < 16) sreg2 = *reinterpret_cast<const short8*>(Xb + (size_t)r2s*DD + (i0v) + ccw*8); \
  } while(0)

#define K1_WRITEX(bufv) do { \
    *reinterpret_cast<short8*>(&bt[bufv][r0s*64 + ((ccw^(r0s&7))<<3)]) = sreg0; \
    *reinterpret_cast<short8*>(&bt[bufv][r1s*64 + ((ccw^(r1s&7))<<3)]) = sreg1; \
    if (tid < 16) *reinterpret_cast<short8*>(&bt[bufv][r2s*64 + ((ccw^(r2s&7))<<3)]) = sreg2; \
  } while(0)

#define K1_LOADA(Abuf, i0v, khv) do { \
    _Pragma("unroll") \
    for (int c = 0; c < 3; ++c) { \
      _Pragma("unroll") \
      for (int tap = 0; tap < 3; ++tap) \
        Abuf[c*3+tap] = *reinterpret_cast<const short8*>(A0 + (size_t)(c*3+tap)*DD*DD + (i0v) + (khv)*32); \
    } \
  } while(0)

#define K1_MFMAS(Abuf, khv) do { \
    _Pragma("unroll") \
    for (int tap = 0; tap < 3; ++tap) { \
      _Pragma("unroll") \
      for (int ts = 0; ts < 4; ++ts) { \
        int row = ts*16 + ln + tap; \
        short8 bfr = *reinterpret_cast<const short8*>(&bt[cur][row*64 + ((((khv)*4+kg) ^ (row&7))<<3)]); \
        acc[0][ts] = __builtin_amdgcn_mfma_f32_16x16x32_bf16(Abuf[0*3+tap], bfr, acc[0][ts], 0,0,0); \
        acc[1][ts] = __builtin_amdgcn_mfma_f32_16x16x32_bf16(Abuf[1*3+tap], bfr, acc[1][ts], 0,0,0); \
        acc[2][ts] = __builtin_amdgcn_mfma_f32_16x16x32_bf16(Abuf[2*3+tap], bfr, acc[2][ts], 0,0,0); \
      } \
    } \
  } while(0)

  K1_LOADX(0);
  K1_LOADA(ArP, 0, 0);
  K1_WRITEX(0);
  __syncthreads();

  int cur = 0;
  #pragma unroll 1
  for (int p = 0; p < 8; ++p) {
    const int i0 = p*64;
    if (p < 7) K1_LOADX(i0 + 64);
    K1_LOADA(ArQ, i0, 1);
    K1_MFMAS(ArP, 0);
    const int i0n = (p < 7) ? i0 + 64 : 0;
    K1_LOADA(ArP, i0n, 0);
    K1_MFMAS(ArQ, 1);
    if (p < 7) {
      K1_WRITEX(cur ^ 1);
      __syncthreads();
      cur ^= 1;
    }
  }

#undef K1_LOADX
#undef K1_WRITEX
#undef K1_LOADA
#undef K1_MFMAS

  #pragma unroll
  for (int ts=0; ts<4; ++ts) {
    int tg = t0 + ts*16 + ln;
    #pragma unroll
    for (int r=0;r<4;++r) {
      int o = og + kg*4 + r;
      size_t oi = (size_t)(z*DD + o)*WW + tg;
      qbf[oi] = f2bf(acc[0][ts][r] + qb[o]);
      kbf[oi] = f2bf(acc[1][ts][r] + kb[o]);
      vbf[oi] = f2bf(acc[2][ts][r] + vb[o]);
    }
  }
}

// ===== shared pattern for k2/k3/k6: C[64x64] = A(per-wave rows) . B(LDS-staged)^T
// LDS tile: 64 rows x 64 u16 (8 chunks of 8), phys chunk = c ^ (row&7): read/write <=2-way.

// ---------- K2: adj = sigmoid(q.kT * scale), B=k-panel staged ----------
__global__ __launch_bounds__(256) void k2_adj(
    const u16* __restrict__ qbf, const u16* __restrict__ kbf, int zb, float* __restrict__ adjo)
{
  __shared__ u16 bp[2][64*64];
  const int tid = threadIdx.x;
  const int w = tid >> 6, l = tid & 63, ln = l & 15, kg = l >> 4;
  const int d0 = blockIdx.x*64 + w*16;
  const int e0 = blockIdx.y*64;
  const int z  = blockIdx.z;
  const int sc = tid & 7, sr = tid >> 3;          // staging: rows sr, sr+32
  const int sp = sc ^ (sr & 7);
  const int sp2 = sc ^ ((sr+32) & 7);
  const u16* B0 = kbf + (size_t)(z*DD + e0)*WW;
  const u16* Asrc = qbf + (size_t)(z*DD + d0 + ln)*WW + kg*8;

  f32x4 acc[4];
  #pragma unroll
  for (int es=0;es<4;++es) acc[es] = (f32x4){0.f,0.f,0.f,0.f};
  short8 aP0, aP1, aQ0, aQ1, sg0, sg1;

  sg0 = *reinterpret_cast<const short8*>(B0 + (size_t)sr*WW + sc*8);
  sg1 = *reinterpret_cast<const short8*>(B0 + (size_t)(sr+32)*WW + sc*8);
  aP0 = *reinterpret_cast<const short8*>(Asrc);
  aP1 = *reinterpret_cast<const short8*>(Asrc + 32);
  *reinterpret_cast<short8*>(&bp[0][sr*64 + sp*8]) = sg0;
  *reinterpret_cast<short8*>(&bp[0][(sr+32)*64 + sp2*8]) = sg1;
  __syncthreads();

  int cur = 0;
  #pragma unroll 1
  for (int s = 0; s < 4; ++s) {                   // K=256, 64/step
    const int fn = (s+1)*64;
    if (s < 3) {
      sg0 = *reinterpret_cast<const short8*>(B0 + (size_t)sr*WW + fn + sc*8);
      sg1 = *reinterpret_cast<const short8*>(B0 + (size_t)(sr+32)*WW + fn + sc*8);
      aQ0 = *reinterpret_cast<const short8*>(Asrc + fn);
      aQ1 = *reinterpret_cast<const short8*>(Asrc + fn + 32);
    }
    #pragma unroll
    for (int es = 0; es < 4; ++es) {
      int row = es*16 + ln;
      short8 b0 = *reinterpret_cast<const short8*>(&bp[cur][row*64 + ((kg ^ (row&7))<<3)]);
      acc[es] = __builtin_amdgcn_mfma_f32_16x16x32_bf16(aP0, b0, acc[es], 0,0,0);
      short8 b1 = *reinterpret_cast<const short8*>(&bp[cur][row*64 + (((4+kg) ^ (row&7))<<3)]);
      acc[es] = __builtin_amdgcn_mfma_f32_16x16x32_bf16(aP1, b1, acc[es], 0,0,0);
    }
    if (s < 3) {
      *reinterpret_cast<short8*>(&bp[cur^1][sr*64 + sp*8]) = sg0;
      *reinterpret_cast<short8*>(&bp[cur^1][(sr+32)*64 + sp2*8]) = sg1;
      __syncthreads();
      cur ^= 1;
      aP0 = aQ0; aP1 = aQ1;
    }
  }
  const float scale = 0.044194173824159216f;
  #pragma unroll
  for (int es=0; es<4; ++es)
    #pragma unroll
    for (int r=0; r<4; ++r) {
      float sig = 1.f/(1.f + expf(-acc[es][r]*scale));
      adjo[((size_t)(zb+z)*DD + d0 + kg*4 + r)*DD + e0 + es*16 + ln] = sig;
    }
}

// ---------- K3: Whtbf[zh][o][n] = (v @ hW^T + hb)^T, B=hW-panel staged ----------
__global__ __launch_bounds__(256) void k3_wh(
    const u16* __restrict__ vbf, const u16* __restrict__ hWbf, const float* __restrict__ hb,
    u16* __restrict__ Whtbf)
{
  __shared__ u16 bp[2][64*64];
  const int tid = threadIdx.x;
  const int w = tid >> 6, l = tid & 63, ln = l & 15, kg = l >> 4;
  const int n0 = blockIdx.x*64 + w*16;
  const int o0 = blockIdx.y*64;
  const int zh = blockIdx.z, z = zh >> 2, h = zh & 3;
  const int sc = tid & 7, sr = tid >> 3;
  const int sp = sc ^ (sr & 7);
  const int sp2 = sc ^ ((sr+32) & 7);
  const u16* B0 = hWbf + (size_t)(h*NHID + o0)*WW;
  const u16* Asrc = vbf + (size_t)(z*DD + n0 + ln)*WW + kg*8;

  f32x4 acc[4];
  #pragma unroll
  for (int os=0;os<4;++os) acc[os] = (f32x4){0.f,0.f,0.f,0.f};
  short8 aP0, aP1, aQ0, aQ1, sg0, sg1;

  sg0 = *reinterpret_cast<const short8*>(B0 + (size_t)sr*WW + sc*8);
  sg1 = *reinterpret_cast<const short8*>(B0 + (size_t)(sr+32)*WW + sc*8);
  aP0 = *reinterpret_cast<const short8*>(Asrc);
  aP1 = *reinterpret_cast<const short8*>(Asrc + 32);
  *reinterpret_cast<short8*>(&bp[0][sr*64 + sp*8]) = sg0;
  *reinterpret_cast<short8*>(&bp[0][(sr+32)*64 + sp2*8]) = sg1;
  __syncthreads();

  int cur = 0;
  #pragma unroll 1
  for (int s = 0; s < 4; ++s) {                   // K=256
    const int fn = (s+1)*64;
    if (s < 3) {
      sg0 = *reinterpret_cast<const short8*>(B0 + (size_t)sr*WW + fn + sc*8);
      sg1 = *reinterpret_cast<const short8*>(B0 + (size_t)(sr+32)*WW + fn + sc*8);
      aQ0 = *reinterpret_cast<const short8*>(Asrc + fn);
      aQ1 = *reinterpret_cast<const short8*>(Asrc + fn + 32);
    }
    #pragma unroll
    for (int os = 0; os < 4; ++os) {
      int row = os*16 + ln;
      short8 b0 = *reinterpret_cast<const short8*>(&bp[cur][row*64 + ((kg ^ (row&7))<<3)]);
      acc[os] = __builtin_amdgcn_mfma_f32_16x16x32_bf16(aP0, b0, acc[os], 0,0,0);
      short8 b1 = *reinterpret_cast<const short8*>(&bp[cur][row*64 + (((4+kg) ^ (row&7))<<3)]);
      acc[os] = __builtin_amdgcn_mfma_f32_16x16x32_bf16(aP1, b1, acc[os], 0,0,0);
    }
    if (s < 3) {
      *reinterpret_cast<short8*>(&bp[cur^1][sr*64 + sp*8]) = sg0;
      *reinterpret_cast<short8*>(&bp[cur^1][(sr+32)*64 + sp2*8]) = sg1;
      __syncthreads();
      cur ^= 1;
      aP0 = aQ0; aP1 = aQ1;
    }
  }
  #pragma unroll
  for (int os=0; os<4; ++os)
    #pragma unroll
    for (int r=0; r<4; ++r) {
      int o = o0 + os*16 + ln;
      int n = n0 + kg*4 + r;
      Whtbf[((size_t)zh*NHID + o)*DD + n] = f2bf(acc[os][r] + hb[h*NHID + o]);
    }
}

// ---------- K4: e1h/e2h ----------
__global__ __launch_bounds__(256) void k4_eheads(
    const u16* __restrict__ vbf,
    const float* __restrict__ ahat_i, const float* __restrict__ ahat_j,
    const float* __restrict__ cvec,
    float* __restrict__ e1, float* __restrict__ e2)
{
  int row = blockIdx.x*4 + (threadIdx.x >> 6);   // row = zh*512 + n
  int lane = threadIdx.x & 63;
  int zh = row >> 9, n = row & 511;
  int z = zh >> 2, h = zh & 3;
  BF4 v4; v4.v = *reinterpret_cast<const ushort4*>(vbf + ((size_t)(z*DD + n))*WW + lane*4);
  const float* aif = ahat_i + h*WW + lane*4;
  const float* ajf = ahat_j + h*WW + lane*4;
  float a1 = 0.f, a2 = 0.f;
  #pragma unroll
  for (int j = 0; j < 4; ++j) {
    float vf = bf2f(v4.u[j]);
    a1 += vf * aif[j];
    a2 += vf * ajf[j];
  }
  #pragma unroll
  for (int off = 32; off >= 1; off >>= 1) { a1 += __shfl_xor(a1, off); a2 += __shfl_xor(a2, off); }
  if (lane == 0) { e1[row] = a1 + cvec[h]; e2[row] = a2 + cvec[4+h]; }
}

// swizzled att chunk index
__device__ __forceinline__ int attsw(int c, int row) {
  return c ^ ((c >> 3) & 7) ^ (row & 7);
}

// ---------- K5: heads attention; os-split waves, depth-3 B prefetch ----------
__global__ __launch_bounds__(256) void k5_attn(
    const float* __restrict__ e1h, const float* __restrict__ e2h,
    const u16* __restrict__ Whtbf, u16* __restrict__ hcatbf)
{
  __shared__ u16 att[64*512];
  __shared__ float inv_lds[64];
  const int nb = blockIdx.x, zh = blockIdx.y;
  const int z = zh >> 2, h = zh & 3;
  const int n0 = nb*64;
  const int tid = threadIdx.x;

  const int r = tid >> 2, qd = tid & 3;
  const float e1n = e1h[(size_t)zh*DD + n0 + r];
  const float* e2r = e2h + (size_t)zh*DD + qd*128;
  float lmax = -1e30f;
  for (int j = 0; j < 128; ++j) {
    float e = e1n + e2r[j];
    e = (e > 0.f) ? e : 0.1f*e;
    lmax = fmaxf(lmax, e);
  }
  lmax = fmaxf(lmax, __shfl_xor(lmax, 1));
  lmax = fmaxf(lmax, __shfl_xor(lmax, 2));
  float lsum = 0.f;
  for (int jc = 0; jc < 16; ++jc) {
    BF8 pk;
    #pragma unroll
    for (int jj = 0; jj < 8; ++jj) {
      float e = e1n + e2r[jc*8 + jj];
      e = (e > 0.f) ? e : 0.1f*e;
      float p = expf(e - lmax);
      lsum += p;
      pk.u[jj] = f2bf(p);
    }
    int c = qd*16 + jc;
    *reinterpret_cast<short8*>(&att[r*512 + attsw(c, r)*8]) = pk.v;
  }
  lsum += __shfl_xor(lsum, 1);
  lsum += __shfl_xor(lsum, 2);
  if ((tid & 3) == 0) inv_lds[r] = 1.f / lsum;
  __syncthreads();

  const int w = tid >> 6, l = tid & 63, ln = l & 15, kg = l >> 4;
  const u16* B0 = Whtbf + ((size_t)zh*NHID + w*32 + ln)*DD + kg*8;
  f32x4 acc[4][2];
  #pragma unroll
  for (int ns=0; ns<4; ++ns) { acc[ns][0] = (f32x4){0,0,0,0}; acc[ns][1] = (f32x4){0,0,0,0}; }

  short8 Pb0,Pb1,Qb0,Qb1,Rb0,Rb1,Sb0,Sb1;
#define K5_LDB(R0,R1,kkv) do { int kc = ((kkv) < 16) ? (kkv) : 0; \
    R0 = *reinterpret_cast<const short8*>(B0 + (size_t)kc*32); \
    R1 = *reinterpret_cast<const short8*>(B0 + (size_t)16*DD + (size_t)kc*32); } while(0)
#define K5_MM(R0,R1,kkv) do { \
    _Pragma("unroll") \
    for (int ns = 0; ns < 4; ++ns) { \
      int row = ns*16 + ln; int c = (kkv)*4 + kg; \
      short8 af = *reinterpret_cast<const short8*>(&att[row*512 + attsw(c,row)*8]); \
      acc[ns][0] = __builtin_amdgcn_mfma_f32_16x16x32_bf16(af, R0, acc[ns][0], 0,0,0); \
      acc[ns][1] = __builtin_amdgcn_mfma_f32_16x16x32_bf16(af, R1, acc[ns][1], 0,0,0); \
    } } while(0)

  K5_LDB(Pb0,Pb1,0); K5_LDB(Qb0,Qb1,1); K5_LDB(Rb0,Rb1,2);
  #pragma unroll 1
  for (int kk = 0; kk < 16; kk += 4) {
    K5_LDB(Sb0,Sb1,kk+3); K5_MM(Pb0,Pb1,kk);
    K5_LDB(Pb0,Pb1,kk+4); K5_MM(Qb0,Qb1,kk+1);
    K5_LDB(Qb0,Qb1,kk+5); K5_MM(Rb0,Rb1,kk+2);
    K5_LDB(Rb0,Rb1,kk+6); K5_MM(Sb0,Sb1,kk+3);
  }
#undef K5_LDB
#undef K5_MM

  #pragma unroll
  for (int ns = 0; ns < 4; ++ns)
    #pragma unroll
    for (int rr = 0; rr < 4; ++rr) {
      int n = ns*16 + kg*4 + rr;
      float inv = inv_lds[n];
      #pragma unroll
      for (int j = 0; j < 2; ++j) {
        float s = acc[ns][j][rr] * inv;
        s = (s > 0.f) ? s : expm1f(s);
        hcatbf[((size_t)z*DD + n0 + n)*DD + h*NHID + w*32 + j*16 + ln] = f2bf(s);
      }
    }
}

// ---------- K6: Wh2tbf[z][o][n] = (hcat @ oW^T + ob)^T, B=oW-panel staged ----------
__global__ __launch_bounds__(256) void k6_wh2(
    const u16* __restrict__ hcatbf, const u16* __restrict__ oWbf, const float* __restrict__ ob,
    u16* __restrict__ Wh2tbf)
{
  __shared__ u16 bp[2][64*64];
  const int tid = threadIdx.x;
  const int w = tid >> 6, l = tid & 63, ln = l & 15, kg = l >> 4;
  const int n0 = blockIdx.x*64 + w*16;
  const int o0 = blockIdx.y*64;
  const int z  = blockIdx.z;
  const int sc = tid & 7, sr = tid >> 3;
  const int sp = sc ^ (sr & 7);
  const int sp2 = sc ^ ((sr+32) & 7);
  const u16* B0 = oWbf + (size_t)o0*DD;
  const u16* Asrc = hcatbf + (size_t)(z*DD + n0 + ln)*DD + kg*8;

  f32x4 acc[4];
  #pragma unroll
  for (int os=0;os<4;++os) acc[os] = (f32x4){0.f,0.f,0.f,0.f};
  short8 aP0, aP1, aQ0, aQ1, sg0, sg1;

  sg0 = *reinterpret_cast<const short8*>(B0 + (size_t)sr*DD + sc*8);
  sg1 = *reinterpret_cast<const short8*>(B0 + (size_t)(sr+32)*DD + sc*8);
  aP0 = *reinterpret_cast<const short8*>(Asrc);
  aP1 = *reinterpret_cast<const short8*>(Asrc + 32);
  *reinterpret_cast<short8*>(&bp[0][sr*64 + sp*8]) = sg0;
  *reinterpret_cast<short8*>(&bp[0][(sr+32)*64 + sp2*8]) = sg1;
  __syncthreads();

  int cur = 0;
  #pragma unroll 1
  for (int s = 0; s < 8; ++s) {                   // K=512
    const int fn = (s+1)*64;
    if (s < 7) {
      sg0 = *reinterpret_cast<const short8*>(B0 + (size_t)sr*DD + fn + sc*8);
      sg1 = *reinterpret_cast<const short8*>(B0 + (size_t)(sr+32)*DD + fn + sc*8);
      aQ0 = *reinterpret_cast<const short8*>(Asrc + fn);
      aQ1 = *reinterpret_cast<const short8*>(Asrc + fn + 32);
    }
    #pragma unroll
    for (int os = 0; os < 4; ++os) {
      int row = os*16 + ln;
      short8 b0 = *reinterpret_cast<const short8*>(&bp[cur][row*64 + ((kg ^ (row&7))<<3)]);
      acc[os] = __builtin_amdgcn_mfma_f32_16x16x32_bf16(aP0, b0, acc[os], 0,0,0);
      short8 b1 = *reinterpret_cast<const short8*>(&bp[cur][row*64 + (((4+kg) ^ (row&7))<<3)]);
      acc[os] = __builtin_amdgcn_mfma_f32_16x16x32_bf16(aP1, b1, acc[os], 0,0,0);
    }
    if (s < 7) {
      *reinterpret_cast<short8*>(&bp[cur^1][sr*64 + sp*8]) = sg0;
      *reinterpret_cast<short8*>(&bp[cur^1][(sr+32)*64 + sp2*8]) = sg1;
      __syncthreads();
      cur ^= 1;
      aP0 = aQ0; aP1 = aQ1;
    }
  }
  #pragma unroll
  for (int os=0; os<4; ++os)
    #pragma unroll
    for (int r=0; r<4; ++r) {
      int o = o0 + os*16 + ln;
      int n = n0 + kg*4 + r;
      Wh2tbf[((size_t)z*WW + o)*DD + n] = f2bf(acc[os][r] + ob[o]);
    }
}

// ---------- K7: e1o/e2o ----------
__global__ __launch_bounds__(256) void k7_eout(
    const u16* __restrict__ hcatbf,
    const float* __restrict__ oahat_i, const float* __restrict__ oahat_j,
    const float* __restrict__ cvec,
    float* __restrict__ e1, float* __restrict__ e2)
{
  int row = blockIdx.x*4 + (threadIdx.x >> 6);
  int lane = threadIdx.x & 63;
  BF8 v8; v8.v = *reinterpret_cast<const short8*>(hcatbf + (size_t)row*DD + lane*8);
  float a1 = 0.f, a2 = 0.f;
  #pragma unroll
  for (int j = 0; j < 8; ++j) {
    float vf = bf2f(v8.u[j]);
    a1 += vf * oahat_i[lane*8 + j];
    a2 += vf * oahat_j[lane*8 + j];
  }
  #pragma unroll
  for (int off = 32; off >= 1; off >>= 1) { a1 += __shfl_xor(a1, off); a2 += __shfl_xor(a2, off); }
  if (lane == 0) { e1[row] = a1 + cvec[8]; e2[row] = a2 + cvec[9]; }
}

// ---------- K8a: out attention PV; os-split waves, depth-3 prefetch -> g f32 (elu) ----------
__global__ __launch_bounds__(256) void k8_pv(
    const float* __restrict__ e1o, const float* __restrict__ e2o,
    const u16* __restrict__ Wh2tbf, float* __restrict__ g)
{
  __shared__ u16 att[64*512];
  __shared__ float inv_lds[64];
  const int nb = blockIdx.x, z = blockIdx.y, oh = blockIdx.z;
  const int n0 = nb*64;
  const int tid = threadIdx.x;

  const int r = tid >> 2, qd = tid & 3;
  const float e1n = e1o[(size_t)z*DD + n0 + r];
  const float* e2r = e2o + (size_t)z*DD + qd*128;
  float lmax = -1e30f;
  for (int j = 0; j < 128; ++j) {
    float e = e1n + e2r[j];
    e = (e > 0.f) ? e : 0.1f*e;
    lmax = fmaxf(lmax, e);
  }
  lmax = fmaxf(lmax, __shfl_xor(lmax, 1));
  lmax = fmaxf(lmax, __shfl_xor(lmax, 2));
  float lsum = 0.f;
  for (int jc = 0; jc < 16; ++jc) {
    BF8 pk;
    #pragma unroll
    for (int jj = 0; jj < 8; ++jj) {
      float e = e1n + e2r[jc*8 + jj];
      e = (e > 0.f) ? e : 0.1f*e;
      float p = expf(e - lmax);
      lsum += p;
      pk.u[jj] = f2bf(p);
    }
    int c = qd*16 + jc;
    *reinterpret_cast<short8*>(&att[r*512 + attsw(c, r)*8]) = pk.v;
  }
  lsum += __shfl_xor(lsum, 1);
  lsum += __shfl_xor(lsum, 2);
  if ((tid & 3) == 0) inv_lds[r] = 1.f / lsum;
  __syncthreads();

  const int w = tid >> 6, l = tid & 63, ln = l & 15, kg = l >> 4;
  const u16* B0 = Wh2tbf + ((size_t)z*WW + oh*128 + w*32 + ln)*DD + kg*8;
  f32x4 acc[4][2];
  #pragma unroll
  for (int ns=0; ns<4; ++ns) { acc[ns][0] = (f32x4){0,0,0,0}; acc[ns][1] = (f32x4){0,0,0,0}; }

  short8 Pb0,Pb1,Qb0,Qb1,Rb0,Rb1,Sb0,Sb1;
#define K8_LDB(R0,R1,kkv) do { int kc = ((kkv) < 16) ? (kkv) : 0; \
    R0 = *reinterpret_cast<const short8*>(B0 + (size_t)kc*32); \
    R1 = *reinterpret_cast<const short8*>(B0 + (size_t)16*DD + (size_t)kc*32); } while(0)
#define K8_MM(R0,R1,kkv) do { \
    _Pragma("unroll") \
    for (int ns = 0; ns < 4; ++ns) { \
      int row = ns*16 + ln; int c = (kkv)*4 + kg; \
      short8 af = *reinterpret_cast<const short8*>(&att[row*512 + attsw(c,row)*8]); \
      acc[ns][0] = __builtin_amdgcn_mfma_f32_16x16x32_bf16(af, R0, acc[ns][0], 0,0,0); \
      acc[ns][1] = __builtin_amdgcn_mfma_f32_16x16x32_bf16(af, R1, acc[ns][1], 0,0,0); \
    } } while(0)

  K8_LDB(Pb0,Pb1,0); K8_LDB(Qb0,Qb1,1); K8_LDB(Rb0,Rb1,2);
  #pragma unroll 1
  for (int kk = 0; kk < 16; kk += 4) {
    K8_LDB(Sb0,Sb1,kk+3); K8_MM(Pb0,Pb1,kk);
    K8_LDB(Pb0,Pb1,kk+4); K8_MM(Qb0,Qb1,kk+1);
    K8_LDB(Qb0,Qb1,kk+5); K8_MM(Rb0,Rb1,kk+2);
    K8_LDB(Rb0,Rb1,kk+6); K8_MM(Sb0,Sb1,kk+3);
  }
#undef K8_LDB
#undef K8_MM

  #pragma unroll
  for (int ns = 0; ns < 4; ++ns)
    #pragma unroll
    for (int rr = 0; rr < 4; ++rr) {
      int n = ns*16 + kg*4 + rr;
      float inv = inv_lds[n];
      #pragma unroll
      for (int j = 0; j < 2; ++j) {
        float val = acc[ns][j][rr] * inv;
        val = (val > 0.f) ? val : expm1f(val);    // elu
        g[((size_t)z*DD + n0 + n)*WW + oh*128 + w*32 + j*16 + ln] = val;
      }
    }
}

// ---------- K8b: row log_softmax over o(256) -> gaty bf16 ----------
__global__ __launch_bounds__(256) void k8_lsm(
    const float* __restrict__ g, u16* __restrict__ gatybf)
{
  int row = blockIdx.x*4 + (threadIdx.x >> 6);
  int lane = threadIdx.x & 63;
  const float* gr = g + (size_t)row*WW;
  float v0 = gr[lane], v1 = gr[lane+64], v2 = gr[lane+128], v3 = gr[lane+192];
  float mx = fmaxf(fmaxf(v0,v1), fmaxf(v2,v3));
  #pragma unroll
  for (int off = 32; off >= 1; off >>= 1) mx = fmaxf(mx, __shfl_xor(mx, off));
  float sm = expf(v0-mx) + expf(v1-mx) + expf(v2-mx) + expf(v3-mx);
  #pragma unroll
  for (int off = 32; off >= 1; off >>= 1) sm += __shfl_xor(sm, off);
  float lg = mx + logf(sm);
  u16* go = gatybf + (size_t)row*WW;
  go[lane]     = f2bf(v0 - lg);
  go[lane+64]  = f2bf(v1 - lg);
  go[lane+128] = f2bf(v2 - lg);
  go[lane+192] = f2bf(v3 - lg);
}

// ---------- K9: out = gaty^T @ pW^T + pb ----------
__global__ __launch_bounds__(256) void k9_proj(
    const u16* __restrict__ gatybf, const u16* __restrict__ pWbf, const float* __restrict__ pb,
    int zb, float* __restrict__ out0)
{
  __shared__ u16 gt[64*40];
  const int t0 = blockIdx.x*64, d0 = blockIdx.y*64, z = blockIdx.z;
  const int tid = threadIdx.x;
  const int w = tid >> 6, l = tid & 63, ln = l & 15, kg = l >> 4;
  const int el = tid >> 3, t8 = tid & 7;
  f32x4 acc[4];
  #pragma unroll
  for (int os=0;os<4;++os) acc[os] = (f32x4){0.f,0.f,0.f,0.f};
  for (int e0 = 0; e0 < DD; e0 += 32) {
    __syncthreads();
    BF8 g8;
    g8.v = *reinterpret_cast<const short8*>(gatybf + ((size_t)z*DD + e0 + el)*WW + t0 + t8*8);
    #pragma unroll
    for (int j = 0; j < 8; ++j) gt[(t8*8 + j)*40 + el] = g8.u[j];
    __syncthreads();
    short8 a = *reinterpret_cast<const short8*>(&gt[(w*16 + ln)*40 + kg*8]);
    #pragma unroll
    for (int os = 0; os < 4; ++os) {
      short8 b = *reinterpret_cast<const short8*>(pWbf + (size_t)(d0 + os*16 + ln)*DD + e0 + kg*8);
      acc[os] = __builtin_amdgcn_mfma_f32_16x16x32_bf16(a, b, acc[os], 0,0,0);
    }
  }
  #pragma unroll
  for (int os=0; os<4; ++os)
    #pragma unroll
    for (int rr=0; rr<4; ++rr) {
      int t = t0 + w*16 + kg*4 + rr;
      int d = d0 + os*16 + ln;
      out0[((size_t)(zb+z)*WW + t)*DD + d] = acc[os][rr] + pb[d];
    }
}

extern "C" void kernel_launch(void* const* d_in, const int* in_sizes, int n_in,
                              void* d_out, int out_size, void* d_ws, size_t ws_size,
                              hipStream_t stream)
{
  const float* x   = (const float*)d_in[0];
  const float* qW  = (const float*)d_in[1];
  const float* qb  = (const float*)d_in[2];
  const float* kW  = (const float*)d_in[3];
  const float* kb  = (const float*)d_in[4];
  const float* vW  = (const float*)d_in[5];
  const float* vb  = (const float*)d_in[6];
  const float* hW  = (const float*)d_in[7];
  const float* hb  = (const float*)d_in[8];
  const float* hai = (const float*)d_in[9];
  const float* haib= (const float*)d_in[10];
  const float* haj = (const float*)d_in[11];
  const float* hajb= (const float*)d_in[12];
  const float* oW  = (const float*)d_in[13];
  const float* ob  = (const float*)d_in[14];
  const float* oai = (const float*)d_in[15];
  const float* oaib= (const float*)d_in[16];
  const float* oaj = (const float*)d_in[17];
  const float* oajb= (const float*)d_in[18];
  const float* pW  = (const float*)d_in[19];
  const float* pb  = (const float*)d_in[20];

  float* out0 = (float*)d_out;                   // [B,W,D] f32
  float* adjo = out0 + (size_t)BB*WW*DD;         // [B,D,D] f32

  // static region (float offsets)
  float* ws      = (float*)d_ws;
  u16*   Wt      = (u16*)(ws + 0);           // 1,179,648 f
  u16*   hWbf    = (u16*)(ws + 1179648);     //    65,536 f
  u16*   oWbf    = (u16*)(ws + 1245184);     //    65,536 f
  u16*   pWbf    = (u16*)(ws + 1310720);     //   131,072 f
  float* ahat_i  = ws + 1441792;
  float* ahat_j  = ws + 1442816;
  float* oahat_i = ws + 1443840;
  float* oahat_j = ws + 1444352;
  float* cvec    = ws + 1444864;
  float* e1h     = ws + 1444880;             //    65,536 f (CB=32 max)
  float* e2h     = ws + 1510416;
  float* e1o     = ws + 1575952;             //    16,384 f
  float* e2o     = ws + 1592336;
  const size_t X0 = 1608720;                 // dynamic region start

  // per-CB dynamic: xpad 66,048 + vbf 65,536 + qbf 65,536 + kbf 65,536 + Whtbf 131,072 = 393,728 f
  int CB = 4;
  {
    const int cand[3] = {32, 16, 8};
    for (int i = 0; i < 3; ++i) {
      size_t need = (X0 + (size_t)cand[i]*393728) * 4;
      if (need <= ws_size) { CB = cand[i]; break; }
    }
  }

  u16* xpad   = (u16*)(ws + X0);                        // CB*66,048 f  ([z][258][512])
  u16* vbf    = (u16*)(ws + X0 + (size_t)CB*66048);     // CB*65,536 f
  u16* qbf    = (u16*)(ws + X0 + (size_t)CB*131584);    // CB*65,536 f
  u16* kbf    = (u16*)(ws + X0 + (size_t)CB*197120);    // CB*65,536 f
  u16* Whtbf  = (u16*)(ws + X0 + (size_t)CB*262656);    // CB*131,072 f
  // overlays (lifetimes: xpad dead after k1; vbf dead after k4; qbf,kbf dead after k2;
  // hcatbf dead after k7; Whtbf dead after k5)
  u16*   hcatbf = (u16*)(ws + X0);                      // over xpad+vbf
  float* g      = (float*)(ws + X0);                    // over hcatbf region (k8 phase)
  u16*   gatybf = (u16*)(ws + X0 + (size_t)CB*131584);  // over qbf
  u16*   Wh2tbf = (u16*)(ws + X0 + (size_t)CB*197120);  // over kbf

  kprep_w<<<dim3((3*DD*DD + 255)/256), 256, 0, stream>>>(qW, kW, vW, Wt);
  kcvt<<<dim3((NHEADS*NHID*WW + 255)/256), 256, 0, stream>>>(hW, hWbf, NHEADS*NHID*WW);
  kcvt<<<dim3((WW*DD + 255)/256), 256, 0, stream>>>(oW, oWbf, WW*DD);
  kcvt<<<dim3((DD*DD + 255)/256), 256, 0, stream>>>(pW, pWbf, DD*DD);
  kprep_a<<<dim3(13), 256, 0, stream>>>(hW, hai, haib, haj, hajb, hb,
                                        oW, oai, oaib, oaj, oajb, ob,
                                        ahat_i, ahat_j, oahat_i, oahat_j, cvec);

  for (int zb = 0; zb < BB; zb += CB) {
    int nrow8 = CB*258*64;
    kprep_x  <<<dim3((nrow8 + 255)/256), 256, 0, stream>>>(x, zb, nrow8, xpad);
    k1_mfma  <<<dim3(32*CB), 256, 0, stream>>>(xpad, Wt, qb, kb, vb, qbf, kbf, vbf);
    k2_adj   <<<dim3(DD/64, DD/64, CB), 256, 0, stream>>>(qbf, kbf, zb, adjo);
    k3_wh    <<<dim3(DD/64, NHID/64, CB*NHEADS), 256, 0, stream>>>(vbf, hWbf, hb, Whtbf);
    k4_eheads<<<dim3(CB*NHEADS*DD/4), 256, 0, stream>>>(vbf, ahat_i, ahat_j, cvec, e1h, e2h);
    k5_attn  <<<dim3(DD/64, CB*NHEADS), 256, 0, stream>>>(e1h, e2h, Whtbf, hcatbf);
    k6_wh2   <<<dim3(DD/64, WW/64, CB), 256, 0, stream>>>(hcatbf, oWbf, ob, Wh2tbf);
    k7_eout  <<<dim3(CB*DD/4), 256, 0, stream>>>(hcatbf, oahat_i, oahat_j, cvec, e1o, e2o);
    k8_pv    <<<dim3(DD/64, CB, 2), 256, 0, stream>>>(e1o, e2o, Wh2tbf, g);
    k8_lsm   <<<dim3(CB*128), 256, 0, stream>>>(g, gatybf);
    k9_proj  <<<dim3(WW/64, DD/64, CB), 256, 0, stream>>>(gatybf, pWbf, pb, zb, out0);
  }
}

// Round 13
// 324.108 us; speedup vs baseline: 1.6497x; 1.0621x over previous
//
#include <hip/hip_runtime.h>
#include <math.h>

typedef unsigned short u16;
typedef __attribute__((ext_vector_type(8))) short short8;
typedef __attribute__((ext_vector_type(4))) float f32x4;

#define BB 32
#define WW 256
#define DD 512
#define NHEADS 4
#define NHID 128

__device__ __forceinline__ u16 f2bf(float f) {
  union { float f; unsigned int i; } x; x.f = f;
  unsigned int i = x.i;
  i += 0x7fffu + ((i >> 16) & 1u);
  return (u16)(i >> 16);
}
__device__ __forceinline__ float bf2f(u16 u) {
  union { float f; unsigned int i; } x; x.i = ((unsigned int)u) << 16; return x.f;
}

union BF8 { short8 v; u16 u[8]; };
union BF4 { ushort4 v; u16 u[4]; };

// ---------- prep (once) ----------
__global__ __launch_bounds__(256) void kprep_w(
    const float* __restrict__ qW, const float* __restrict__ kW, const float* __restrict__ vW,
    u16* __restrict__ Wt)
{
  int idx = blockIdx.x*256 + threadIdx.x;     // (c, o, i)
  if (idx >= 3*DD*DD) return;
  int c = idx >> 18;
  int oi = idx & (DD*DD - 1);
  int i = oi & (DD-1);
  int o = oi >> 9;
  const float* W = (c==0) ? qW : (c==1) ? kW : vW;
  float w0 = W[oi*3+0], w1 = W[oi*3+1], w2 = W[oi*3+2];
  Wt[((size_t)(c*3+0)*DD + o)*DD + i] = f2bf(w0);
  Wt[((size_t)(c*3+1)*DD + o)*DD + i] = f2bf(w1);
  Wt[((size_t)(c*3+2)*DD + o)*DD + i] = f2bf(w2);
}

__global__ __launch_bounds__(256) void kcvt(const float* __restrict__ s, u16* __restrict__ d, int n) {
  int i = blockIdx.x*256 + threadIdx.x;
  if (i < n) d[i] = f2bf(s[i]);
}

__global__ __launch_bounds__(256) void kprep_a(
    const float* __restrict__ hW, const float* __restrict__ hai, const float* __restrict__ haib,
    const float* __restrict__ haj, const float* __restrict__ hajb,
    const float* __restrict__ hb,
    const float* __restrict__ oW, const float* __restrict__ oai, const float* __restrict__ oaib,
    const float* __restrict__ oaj, const float* __restrict__ oajb,
    const float* __restrict__ ob,
    float* __restrict__ ahat_i, float* __restrict__ ahat_j,
    float* __restrict__ oahat_i, float* __restrict__ oahat_j,
    float* __restrict__ cvec)
{
  int idx = blockIdx.x*256 + threadIdx.x;
  if (idx < 1024) {
    int h = idx >> 8, f = idx & 255;
    float s = 0.f;
    for (int o = 0; o < NHID; ++o) s += hW[((size_t)h*NHID + o)*WW + f] * hai[h*NHID + o];
    ahat_i[idx] = s;
  } else if (idx < 2048) {
    int t = idx - 1024; int h = t >> 8, f = t & 255;
    float s = 0.f;
    for (int o = 0; o < NHID; ++o) s += hW[((size_t)h*NHID + o)*WW + f] * haj[h*NHID + o];
    ahat_j[t] = s;
  } else if (idx < 2560) {
    int f = idx - 2048;
    float s = 0.f;
    for (int o = 0; o < WW; ++o) s += oW[(size_t)o*DD + f] * oai[o];
    oahat_i[f] = s;
  } else if (idx < 3072) {
    int f = idx - 2560;
    float s = 0.f;
    for (int o = 0; o < WW; ++o) s += oW[(size_t)o*DD + f] * oaj[o];
    oahat_j[f] = s;
  } else if (idx < 3082) {
    int t = idx - 3072;
    if (t < 4) {
      float s = 0.f;
      for (int o = 0; o < NHID; ++o) s += hb[t*NHID + o]*hai[t*NHID + o];
      cvec[t] = s + haib[t];
    } else if (t < 8) {
      int h = t - 4; float s = 0.f;
      for (int o = 0; o < NHID; ++o) s += hb[h*NHID + o]*haj[h*NHID + o];
      cvec[t] = s + hajb[h];
    } else if (t == 8) {
      float s = 0.f;
      for (int o = 0; o < WW; ++o) s += ob[o]*oai[o];
      cvec[8] = s + oaib[0];
    } else {
      float s = 0.f;
      for (int o = 0; o < WW; ++o) s += ob[o]*oaj[o];
      cvec[9] = s + oajb[0];
    }
  }
}

// x f32 -> xpad bf16 [z][258][512] with zero halo rows (t=-1, t=256)
__global__ __launch_bounds__(256) void kprep_x(
    const float* __restrict__ x, int zb, int nrow8, u16* __restrict__ xpad)
{
  int idx8 = blockIdx.x*256 + threadIdx.x;
  if (idx8 >= nrow8) return;
  int i8 = idx8 & 63;
  int rowg = idx8 >> 6;                       // z*258 + r
  int z = rowg / 258, r = rowg - z*258;
  int t = r - 1;
  BF8 o8;
  if (t >= 0 && t < WW) {
    const float* src = x + ((size_t)(zb+z)*WW + t)*DD + i8*8;
    float4 v0 = *reinterpret_cast<const float4*>(src);
    float4 v1 = *reinterpret_cast<const float4*>(src + 4);
    o8.u[0]=f2bf(v0.x); o8.u[1]=f2bf(v0.y); o8.u[2]=f2bf(v0.z); o8.u[3]=f2bf(v0.w);
    o8.u[4]=f2bf(v1.x); o8.u[5]=f2bf(v1.y); o8.u[6]=f2bf(v1.z); o8.u[7]=f2bf(v1.w);
  } else {
    #pragma unroll
    for (int j = 0; j < 8; ++j) o8.u[j] = 0;
  }
  *reinterpret_cast<short8*>(xpad + (size_t)rowg*DD + i8*8) = o8.v;
}

// ---------- K1: conv via MFMA; 64o x 128t tile; B LDS-staged (swizzled, dbuf) ----------
// Per phase: 9 A-frag loads feed 72 MFMAs (vs 36 at 64t) -> 2x latency cover, 1/2 A traffic.
__global__ __launch_bounds__(256) void k1_mfma(
    const u16* __restrict__ xpad, const u16* __restrict__ Wt,
    const float* __restrict__ qb, const float* __restrict__ kb, const float* __restrict__ vb,
    u16* __restrict__ qbf, u16* __restrict__ kbf, u16* __restrict__ vbf)
{
  __shared__ u16 bt[2][130*64];              // 2 x 16.6 KB
  const int tid = threadIdx.x;
  const int w  = tid >> 6;
  const int l  = tid & 63;
  const int ln = l & 15;
  const int kg = l >> 4;
  const int og = blockIdx.x * 64 + w * 16;
  const int t0 = blockIdx.y * 128;
  const int z  = blockIdx.z;

  const u16* A0 = Wt + (size_t)(og + ln)*DD + kg*8;
  const u16* Xb = xpad + ((size_t)z*258 + t0)*DD;

  f32x4 acc[3][8];
  #pragma unroll
  for (int c=0;c<3;++c)
    #pragma unroll
    for (int ts=0;ts<8;++ts) acc[c][ts] = (f32x4){0.f,0.f,0.f,0.f};

  short8 ArP[9], ArQ[9];
  short8 sg0, sg1, sg2, sg3, sg4;
  const int ccw = tid & 7;
  const int rs = tid >> 3;                   // staging rows rs+32n (n=0..3); tid<16: row 128+rs

#define K1_LOADX(i0v) do { \
    sg0 = *reinterpret_cast<const short8*>(Xb + (size_t)rs*DD + (i0v) + ccw*8); \
    sg1 = *reinterpret_cast<const short8*>(Xb + (size_t)(rs+32)*DD + (i0v) + ccw*8); \
    sg2 = *reinterpret_cast<const short8*>(Xb + (size_t)(rs+64)*DD + (i0v) + ccw*8); \
    sg3 = *reinterpret_cast<const short8*>(Xb + (size_t)(rs+96)*DD + (i0v) + ccw*8); \
    if (tid < 16) sg4 = *reinterpret_cast<const short8*>(Xb + (size_t)(rs+128)*DD + (i0v) + ccw*8); \
  } while(0)

#define K1_WRITEX(bufv) do { \
    *reinterpret_cast<short8*>(&bt[bufv][rs*64 + ((ccw^(rs&7))<<3)]) = sg0; \
    *reinterpret_cast<short8*>(&bt[bufv][(rs+32)*64 + ((ccw^((rs+32)&7))<<3)]) = sg1; \
    *reinterpret_cast<short8*>(&bt[bufv][(rs+64)*64 + ((ccw^((rs+64)&7))<<3)]) = sg2; \
    *reinterpret_cast<short8*>(&bt[bufv][(rs+96)*64 + ((ccw^((rs+96)&7))<<3)]) = sg3; \
    if (tid < 16) *reinterpret_cast<short8*>(&bt[bufv][(rs+128)*64 + ((ccw^((rs+128)&7))<<3)]) = sg4; \
  } while(0)

#define K1_LOADA(Abuf, i0v, khv) do { \
    _Pragma("unroll") \
    for (int c = 0; c < 3; ++c) { \
      _Pragma("unroll") \
      for (int tap = 0; tap < 3; ++tap) \
        Abuf[c*3+tap] = *reinterpret_cast<const short8*>(A0 + (size_t)(c*3+tap)*DD*DD + (i0v) + (khv)*32); \
    } \
  } while(0)

#define K1_MFMAS(Abuf, khv) do { \
    _Pragma("unroll") \
    for (int tap = 0; tap < 3; ++tap) { \
      _Pragma("unroll") \
      for (int ts = 0; ts < 8; ++ts) { \
        int row = ts*16 + ln + tap; \
        short8 bfr = *reinterpret_cast<const short8*>(&bt[cur][row*64 + ((((khv)*4+kg) ^ (row&7))<<3)]); \
        acc[0][ts] = __builtin_amdgcn_mfma_f32_16x16x32_bf16(Abuf[0*3+tap], bfr, acc[0][ts], 0,0,0); \
        acc[1][ts] = __builtin_amdgcn_mfma_f32_16x16x32_bf16(Abuf[1*3+tap], bfr, acc[1][ts], 0,0,0); \
        acc[2][ts] = __builtin_amdgcn_mfma_f32_16x16x32_bf16(Abuf[2*3+tap], bfr, acc[2][ts], 0,0,0); \
      } \
    } \
  } while(0)

  K1_LOADX(0);
  K1_LOADA(ArP, 0, 0);
  K1_WRITEX(0);
  __syncthreads();

  int cur = 0;
  #pragma unroll 1
  for (int p = 0; p < 8; ++p) {
    const int i0 = p*64;
    if (p < 7) K1_LOADX(i0 + 64);
    K1_LOADA(ArQ, i0, 1);
    K1_MFMAS(ArP, 0);
    const int i0n = (p < 7) ? i0 + 64 : 0;
    K1_LOADA(ArP, i0n, 0);
    K1_MFMAS(ArQ, 1);
    if (p < 7) {
      K1_WRITEX(cur ^ 1);
      __syncthreads();
      cur ^= 1;
    }
  }

#undef K1_LOADX
#undef K1_WRITEX
#undef K1_LOADA
#undef K1_MFMAS

  #pragma unroll
  for (int ts=0; ts<8; ++ts) {
    int tg = t0 + ts*16 + ln;
    #pragma unroll
    for (int r=0;r<4;++r) {
      int o = og + kg*4 + r;
      size_t oi = (size_t)(z*DD + o)*WW + tg;
      qbf[oi] = f2bf(acc[0][ts][r] + qb[o]);
      kbf[oi] = f2bf(acc[1][ts][r] + kb[o]);
      vbf[oi] = f2bf(acc[2][ts][r] + vb[o]);
    }
  }
}

// ===== shared pattern for k2/k3/k6: C[64x64] = A(per-wave rows) . B(LDS-staged)^T

// ---------- K2: adj = sigmoid(q.kT * scale), B=k-panel staged ----------
__global__ __launch_bounds__(256) void k2_adj(
    const u16* __restrict__ qbf, const u16* __restrict__ kbf, int zb, float* __restrict__ adjo)
{
  __shared__ u16 bp[2][64*64];
  const int tid = threadIdx.x;
  const int w = tid >> 6, l = tid & 63, ln = l & 15, kg = l >> 4;
  const int d0 = blockIdx.x*64 + w*16;
  const int e0 = blockIdx.y*64;
  const int z  = blockIdx.z;
  const int sc = tid & 7, sr = tid >> 3;
  const int sp = sc ^ (sr & 7);
  const int sp2 = sc ^ ((sr+32) & 7);
  const u16* B0 = kbf + (size_t)(z*DD + e0)*WW;
  const u16* Asrc = qbf + (size_t)(z*DD + d0 + ln)*WW + kg*8;

  f32x4 acc[4];
  #pragma unroll
  for (int es=0;es<4;++es) acc[es] = (f32x4){0.f,0.f,0.f,0.f};
  short8 aP0, aP1, aQ0, aQ1, sg0, sg1;

  sg0 = *reinterpret_cast<const short8*>(B0 + (size_t)sr*WW + sc*8);
  sg1 = *reinterpret_cast<const short8*>(B0 + (size_t)(sr+32)*WW + sc*8);
  aP0 = *reinterpret_cast<const short8*>(Asrc);
  aP1 = *reinterpret_cast<const short8*>(Asrc + 32);
  *reinterpret_cast<short8*>(&bp[0][sr*64 + sp*8]) = sg0;
  *reinterpret_cast<short8*>(&bp[0][(sr+32)*64 + sp2*8]) = sg1;
  __syncthreads();

  int cur = 0;
  #pragma unroll 1
  for (int s = 0; s < 4; ++s) {
    const int fn = (s+1)*64;
    if (s < 3) {
      sg0 = *reinterpret_cast<const short8*>(B0 + (size_t)sr*WW + fn + sc*8);
      sg1 = *reinterpret_cast<const short8*>(B0 + (size_t)(sr+32)*WW + fn + sc*8);
      aQ0 = *reinterpret_cast<const short8*>(Asrc + fn);
      aQ1 = *reinterpret_cast<const short8*>(Asrc + fn + 32);
    }
    #pragma unroll
    for (int es = 0; es < 4; ++es) {
      int row = es*16 + ln;
      short8 b0 = *reinterpret_cast<const short8*>(&bp[cur][row*64 + ((kg ^ (row&7))<<3)]);
      acc[es] = __builtin_amdgcn_mfma_f32_16x16x32_bf16(aP0, b0, acc[es], 0,0,0);
      short8 b1 = *reinterpret_cast<const short8*>(&bp[cur][row*64 + (((4+kg) ^ (row&7))<<3)]);
      acc[es] = __builtin_amdgcn_mfma_f32_16x16x32_bf16(aP1, b1, acc[es], 0,0,0);
    }
    if (s < 3) {
      *reinterpret_cast<short8*>(&bp[cur^1][sr*64 + sp*8]) = sg0;
      *reinterpret_cast<short8*>(&bp[cur^1][(sr+32)*64 + sp2*8]) = sg1;
      __syncthreads();
      cur ^= 1;
      aP0 = aQ0; aP1 = aQ1;
    }
  }
  const float scale = 0.044194173824159216f;
  #pragma unroll
  for (int es=0; es<4; ++es)
    #pragma unroll
    for (int r=0; r<4; ++r) {
      float sig = 1.f/(1.f + expf(-acc[es][r]*scale));
      adjo[((size_t)(zb+z)*DD + d0 + kg*4 + r)*DD + e0 + es*16 + ln] = sig;
    }
}

// ---------- K3: Whtbf[zh][o][n] = (v @ hW^T + hb)^T, B=hW-panel staged ----------
__global__ __launch_bounds__(256) void k3_wh(
    const u16* __restrict__ vbf, const u16* __restrict__ hWbf, const float* __restrict__ hb,
    u16* __restrict__ Whtbf)
{
  __shared__ u16 bp[2][64*64];
  const int tid = threadIdx.x;
  const int w = tid >> 6, l = tid & 63, ln = l & 15, kg = l >> 4;
  const int n0 = blockIdx.x*64 + w*16;
  const int o0 = blockIdx.y*64;
  const int zh = blockIdx.z, z = zh >> 2, h = zh & 3;
  const int sc = tid & 7, sr = tid >> 3;
  const int sp = sc ^ (sr & 7);
  const int sp2 = sc ^ ((sr+32) & 7);
  const u16* B0 = hWbf + (size_t)(h*NHID + o0)*WW;
  const u16* Asrc = vbf + (size_t)(z*DD + n0 + ln)*WW + kg*8;

  f32x4 acc[4];
  #pragma unroll
  for (int os=0;os<4;++os) acc[os] = (f32x4){0.f,0.f,0.f,0.f};
  short8 aP0, aP1, aQ0, aQ1, sg0, sg1;

  sg0 = *reinterpret_cast<const short8*>(B0 + (size_t)sr*WW + sc*8);
  sg1 = *reinterpret_cast<const short8*>(B0 + (size_t)(sr+32)*WW + sc*8);
  aP0 = *reinterpret_cast<const short8*>(Asrc);
  aP1 = *reinterpret_cast<const short8*>(Asrc + 32);
  *reinterpret_cast<short8*>(&bp[0][sr*64 + sp*8]) = sg0;
  *reinterpret_cast<short8*>(&bp[0][(sr+32)*64 + sp2*8]) = sg1;
  __syncthreads();

  int cur = 0;
  #pragma unroll 1
  for (int s = 0; s < 4; ++s) {
    const int fn = (s+1)*64;
    if (s < 3) {
      sg0 = *reinterpret_cast<const short8*>(B0 + (size_t)sr*WW + fn + sc*8);
      sg1 = *reinterpret_cast<const short8*>(B0 + (size_t)(sr+32)*WW + fn + sc*8);
      aQ0 = *reinterpret_cast<const short8*>(Asrc + fn);
      aQ1 = *reinterpret_cast<const short8*>(Asrc + fn + 32);
    }
    #pragma unroll
    for (int os = 0; os < 4; ++os) {
      int row = os*16 + ln;
      short8 b0 = *reinterpret_cast<const short8*>(&bp[cur][row*64 + ((kg ^ (row&7))<<3)]);
      acc[os] = __builtin_amdgcn_mfma_f32_16x16x32_bf16(aP0, b0, acc[os], 0,0,0);
      short8 b1 = *reinterpret_cast<const short8*>(&bp[cur][row*64 + (((4+kg) ^ (row&7))<<3)]);
      acc[os] = __builtin_amdgcn_mfma_f32_16x16x32_bf16(aP1, b1, acc[os], 0,0,0);
    }
    if (s < 3) {
      *reinterpret_cast<short8*>(&bp[cur^1][sr*64 + sp*8]) = sg0;
      *reinterpret_cast<short8*>(&bp[cur^1][(sr+32)*64 + sp2*8]) = sg1;
      __syncthreads();
      cur ^= 1;
      aP0 = aQ0; aP1 = aQ1;
    }
  }
  #pragma unroll
  for (int os=0; os<4; ++os)
    #pragma unroll
    for (int r=0; r<4; ++r) {
      int o = o0 + os*16 + ln;
      int n = n0 + kg*4 + r;
      Whtbf[((size_t)zh*NHID + o)*DD + n] = f2bf(acc[os][r] + hb[h*NHID + o]);
    }
}

// ---------- K4: e1h/e2h ----------
__global__ __launch_bounds__(256) void k4_eheads(
    const u16* __restrict__ vbf,
    const float* __restrict__ ahat_i, const float* __restrict__ ahat_j,
    const float* __restrict__ cvec,
    float* __restrict__ e1, float* __restrict__ e2)
{
  int row = blockIdx.x*4 + (threadIdx.x >> 6);   // row = zh*512 + n
  int lane = threadIdx.x & 63;
  int zh = row >> 9, n = row & 511;
  int z = zh >> 2, h = zh & 3;
  BF4 v4; v4.v = *reinterpret_cast<const ushort4*>(vbf + ((size_t)(z*DD + n))*WW + lane*4);
  const float* aif = ahat_i + h*WW + lane*4;
  const float* ajf = ahat_j + h*WW + lane*4;
  float a1 = 0.f, a2 = 0.f;
  #pragma unroll
  for (int j = 0; j < 4; ++j) {
    float vf = bf2f(v4.u[j]);
    a1 += vf * aif[j];
    a2 += vf * ajf[j];
  }
  #pragma unroll
  for (int off = 32; off >= 1; off >>= 1) { a1 += __shfl_xor(a1, off); a2 += __shfl_xor(a2, off); }
  if (lane == 0) { e1[row] = a1 + cvec[h]; e2[row] = a2 + cvec[4+h]; }
}

// swizzled att chunk index
__device__ __forceinline__ int attsw(int c, int row) {
  return c ^ ((c >> 3) & 7) ^ (row & 7);
}

// ---------- K5: heads attention; os-split waves, depth-3 B prefetch ----------
__global__ __launch_bounds__(256) void k5_attn(
    const float* __restrict__ e1h, const float* __restrict__ e2h,
    const u16* __restrict__ Whtbf, u16* __restrict__ hcatbf)
{
  __shared__ u16 att[64*512];
  __shared__ float inv_lds[64];
  const int nb = blockIdx.x, zh = blockIdx.y;
  const int z = zh >> 2, h = zh & 3;
  const int n0 = nb*64;
  const int tid = threadIdx.x;

  const int r = tid >> 2, qd = tid & 3;
  const float e1n = e1h[(size_t)zh*DD + n0 + r];
  const float* e2r = e2h + (size_t)zh*DD + qd*128;
  float lmax = -1e30f;
  for (int j = 0; j < 128; ++j) {
    float e = e1n + e2r[j];
    e = (e > 0.f) ? e : 0.1f*e;
    lmax = fmaxf(lmax, e);
  }
  lmax = fmaxf(lmax, __shfl_xor(lmax, 1));
  lmax = fmaxf(lmax, __shfl_xor(lmax, 2));
  float lsum = 0.f;
  for (int jc = 0; jc < 16; ++jc) {
    BF8 pk;
    #pragma unroll
    for (int jj = 0; jj < 8; ++jj) {
      float e = e1n + e2r[jc*8 + jj];
      e = (e > 0.f) ? e : 0.1f*e;
      float p = expf(e - lmax);
      lsum += p;
      pk.u[jj] = f2bf(p);
    }
    int c = qd*16 + jc;
    *reinterpret_cast<short8*>(&att[r*512 + attsw(c, r)*8]) = pk.v;
  }
  lsum += __shfl_xor(lsum, 1);
  lsum += __shfl_xor(lsum, 2);
  if ((tid & 3) == 0) inv_lds[r] = 1.f / lsum;
  __syncthreads();

  const int w = tid >> 6, l = tid & 63, ln = l & 15, kg = l >> 4;
  const u16* B0 = Whtbf + ((size_t)zh*NHID + w*32 + ln)*DD + kg*8;
  f32x4 acc[4][2];
  #pragma unroll
  for (int ns=0; ns<4; ++ns) { acc[ns][0] = (f32x4){0,0,0,0}; acc[ns][1] = (f32x4){0,0,0,0}; }

  short8 Pb0,Pb1,Qb0,Qb1,Rb0,Rb1,Sb0,Sb1;
#define K5_LDB(R0,R1,kkv) do { int kc = ((kkv) < 16) ? (kkv) : 0; \
    R0 = *reinterpret_cast<const short8*>(B0 + (size_t)kc*32); \
    R1 = *reinterpret_cast<const short8*>(B0 + (size_t)16*DD + (size_t)kc*32); } while(0)
#define K5_MM(R0,R1,kkv) do { \
    _Pragma("unroll") \
    for (int ns = 0; ns < 4; ++ns) { \
      int row = ns*16 + ln; int c = (kkv)*4 + kg; \
      short8 af = *reinterpret_cast<const short8*>(&att[row*512 + attsw(c,row)*8]); \
      acc[ns][0] = __builtin_amdgcn_mfma_f32_16x16x32_bf16(af, R0, acc[ns][0], 0,0,0); \
      acc[ns][1] = __builtin_amdgcn_mfma_f32_16x16x32_bf16(af, R1, acc[ns][1], 0,0,0); \
    } } while(0)

  K5_LDB(Pb0,Pb1,0); K5_LDB(Qb0,Qb1,1); K5_LDB(Rb0,Rb1,2);
  #pragma unroll 1
  for (int kk = 0; kk < 16; kk += 4) {
    K5_LDB(Sb0,Sb1,kk+3); K5_MM(Pb0,Pb1,kk);
    K5_LDB(Pb0,Pb1,kk+4); K5_MM(Qb0,Qb1,kk+1);
    K5_LDB(Qb0,Qb1,kk+5); K5_MM(Rb0,Rb1,kk+2);
    K5_LDB(Rb0,Rb1,kk+6); K5_MM(Sb0,Sb1,kk+3);
  }
#undef K5_LDB
#undef K5_MM

  #pragma unroll
  for (int ns = 0; ns < 4; ++ns)
    #pragma unroll
    for (int rr = 0; rr < 4; ++rr) {
      int n = ns*16 + kg*4 + rr;
      float inv = inv_lds[n];
      #pragma unroll
      for (int j = 0; j < 2; ++j) {
        float s = acc[ns][j][rr] * inv;
        s = (s > 0.f) ? s : expm1f(s);
        hcatbf[((size_t)z*DD + n0 + n)*DD + h*NHID + w*32 + j*16 + ln] = f2bf(s);
      }
    }
}

// ---------- K6: Wh2tbf[z][o][n] = (hcat @ oW^T + ob)^T, B=oW-panel staged ----------
__global__ __launch_bounds__(256) void k6_wh2(
    const u16* __restrict__ hcatbf, const u16* __restrict__ oWbf, const float* __restrict__ ob,
    u16* __restrict__ Wh2tbf)
{
  __shared__ u16 bp[2][64*64];
  const int tid = threadIdx.x;
  const int w = tid >> 6, l = tid & 63, ln = l & 15, kg = l >> 4;
  const int n0 = blockIdx.x*64 + w*16;
  const int o0 = blockIdx.y*64;
  const int z  = blockIdx.z;
  const int sc = tid & 7, sr = tid >> 3;
  const int sp = sc ^ (sr & 7);
  const int sp2 = sc ^ ((sr+32) & 7);
  const u16* B0 = oWbf + (size_t)o0*DD;
  const u16* Asrc = hcatbf + (size_t)(z*DD + n0 + ln)*DD + kg*8;

  f32x4 acc[4];
  #pragma unroll
  for (int os=0;os<4;++os) acc[os] = (f32x4){0.f,0.f,0.f,0.f};
  short8 aP0, aP1, aQ0, aQ1, sg0, sg1;

  sg0 = *reinterpret_cast<const short8*>(B0 + (size_t)sr*DD + sc*8);
  sg1 = *reinterpret_cast<const short8*>(B0 + (size_t)(sr+32)*DD + sc*8);
  aP0 = *reinterpret_cast<const short8*>(Asrc);
  aP1 = *reinterpret_cast<const short8*>(Asrc + 32);
  *reinterpret_cast<short8*>(&bp[0][sr*64 + sp*8]) = sg0;
  *reinterpret_cast<short8*>(&bp[0][(sr+32)*64 + sp2*8]) = sg1;
  __syncthreads();

  int cur = 0;
  #pragma unroll 1
  for (int s = 0; s < 8; ++s) {
    const int fn = (s+1)*64;
    if (s < 7) {
      sg0 = *reinterpret_cast<const short8*>(B0 + (size_t)sr*DD + fn + sc*8);
      sg1 = *reinterpret_cast<const short8*>(B0 + (size_t)(sr+32)*DD + fn + sc*8);
      aQ0 = *reinterpret_cast<const short8*>(Asrc + fn);
      aQ1 = *reinterpret_cast<const short8*>(Asrc + fn + 32);
    }
    #pragma unroll
    for (int os = 0; os < 4; ++os) {
      int row = os*16 + ln;
      short8 b0 = *reinterpret_cast<const short8*>(&bp[cur][row*64 + ((kg ^ (row&7))<<3)]);
      acc[os] = __builtin_amdgcn_mfma_f32_16x16x32_bf16(aP0, b0, acc[os], 0,0,0);
      short8 b1 = *reinterpret_cast<const short8*>(&bp[cur][row*64 + (((4+kg) ^ (row&7))<<3)]);
      acc[os] = __builtin_amdgcn_mfma_f32_16x16x32_bf16(aP1, b1, acc[os], 0,0,0);
    }
    if (s < 7) {
      *reinterpret_cast<short8*>(&bp[cur^1][sr*64 + sp*8]) = sg0;
      *reinterpret_cast<short8*>(&bp[cur^1][(sr+32)*64 + sp2*8]) = sg1;
      __syncthreads();
      cur ^= 1;
      aP0 = aQ0; aP1 = aQ1;
    }
  }
  #pragma unroll
  for (int os=0; os<4; ++os)
    #pragma unroll
    for (int r=0; r<4; ++r) {
      int o = o0 + os*16 + ln;
      int n = n0 + kg*4 + r;
      Wh2tbf[((size_t)z*WW + o)*DD + n] = f2bf(acc[os][r] + ob[o]);
    }
}

// ---------- K7: e1o/e2o ----------
__global__ __launch_bounds__(256) void k7_eout(
    const u16* __restrict__ hcatbf,
    const float* __restrict__ oahat_i, const float* __restrict__ oahat_j,
    const float* __restrict__ cvec,
    float* __restrict__ e1, float* __restrict__ e2)
{
  int row = blockIdx.x*4 + (threadIdx.x >> 6);
  int lane = threadIdx.x & 63;
  BF8 v8; v8.v = *reinterpret_cast<const short8*>(hcatbf + (size_t)row*DD + lane*8);
  float a1 = 0.f, a2 = 0.f;
  #pragma unroll
  for (int j = 0; j < 8; ++j) {
    float vf = bf2f(v8.u[j]);
    a1 += vf * oahat_i[lane*8 + j];
    a2 += vf * oahat_j[lane*8 + j];
  }
  #pragma unroll
  for (int off = 32; off >= 1; off >>= 1) { a1 += __shfl_xor(a1, off); a2 += __shfl_xor(a2, off); }
  if (lane == 0) { e1[row] = a1 + cvec[8]; e2[row] = a2 + cvec[9]; }
}

// ---------- K8a: out attention PV; os-split waves, depth-3 prefetch -> g f32 (elu) ----------
__global__ __launch_bounds__(256) void k8_pv(
    const float* __restrict__ e1o, const float* __restrict__ e2o,
    const u16* __restrict__ Wh2tbf, float* __restrict__ g)
{
  __shared__ u16 att[64*512];
  __shared__ float inv_lds[64];
  const int nb = blockIdx.x, z = blockIdx.y, oh = blockIdx.z;
  const int n0 = nb*64;
  const int tid = threadIdx.x;

  const int r = tid >> 2, qd = tid & 3;
  const float e1n = e1o[(size_t)z*DD + n0 + r];
  const float* e2r = e2o + (size_t)z*DD + qd*128;
  float lmax = -1e30f;
  for (int j = 0; j < 128; ++j) {
    float e = e1n + e2r[j];
    e = (e > 0.f) ? e : 0.1f*e;
    lmax = fmaxf(lmax, e);
  }
  lmax = fmaxf(lmax, __shfl_xor(lmax, 1));
  lmax = fmaxf(lmax, __shfl_xor(lmax, 2));
  float lsum = 0.f;
  for (int jc = 0; jc < 16; ++jc) {
    BF8 pk;
    #pragma unroll
    for (int jj = 0; jj < 8; ++jj) {
      float e = e1n + e2r[jc*8 + jj];
      e = (e > 0.f) ? e : 0.1f*e;
      float p = expf(e - lmax);
      lsum += p;
      pk.u[jj] = f2bf(p);
    }
    int c = qd*16 + jc;
    *reinterpret_cast<short8*>(&att[r*512 + attsw(c, r)*8]) = pk.v;
  }
  lsum += __shfl_xor(lsum, 1);
  lsum += __shfl_xor(lsum, 2);
  if ((tid & 3) == 0) inv_lds[r] = 1.f / lsum;
  __syncthreads();

  const int w = tid >> 6, l = tid & 63, ln = l & 15, kg = l >> 4;
  const u16* B0 = Wh2tbf + ((size_t)z*WW + oh*128 + w*32 + ln)*DD + kg*8;
  f32x4 acc[4][2];
  #pragma unroll
  for (int ns=0; ns<4; ++ns) { acc[ns][0] = (f32x4){0,0,0,0}; acc[ns][1] = (f32x4){0,0,0,0}; }

  short8 Pb0,Pb1,Qb0,Qb1,Rb0,Rb1,Sb0,Sb1;
#define K8_LDB(R0,R1,kkv) do { int kc = ((kkv) < 16) ? (kkv) : 0; \
    R0 = *reinterpret_cast<const short8*>(B0 + (size_t)kc*32); \
    R1 = *reinterpret_cast<const short8*>(B0 + (size_t)16*DD + (size_t)kc*32); } while(0)
#define K8_MM(R0,R1,kkv) do { \
    _Pragma("unroll") \
    for (int ns = 0; ns < 4; ++ns) { \
      int row = ns*16 + ln; int c = (kkv)*4 + kg; \
      short8 af = *reinterpret_cast<const short8*>(&att[row*512 + attsw(c,row)*8]); \
      acc[ns][0] = __builtin_amdgcn_mfma_f32_16x16x32_bf16(af, R0, acc[ns][0], 0,0,0); \
      acc[ns][1] = __builtin_amdgcn_mfma_f32_16x16x32_bf16(af, R1, acc[ns][1], 0,0,0); \
    } } while(0)

  K8_LDB(Pb0,Pb1,0); K8_LDB(Qb0,Qb1,1); K8_LDB(Rb0,Rb1,2);
  #pragma unroll 1
  for (int kk = 0; kk < 16; kk += 4) {
    K8_LDB(Sb0,Sb1,kk+3); K8_MM(Pb0,Pb1,kk);
    K8_LDB(Pb0,Pb1,kk+4); K8_MM(Qb0,Qb1,kk+1);
    K8_LDB(Qb0,Qb1,kk+5); K8_MM(Rb0,Rb1,kk+2);
    K8_LDB(Rb0,Rb1,kk+6); K8_MM(Sb0,Sb1,kk+3);
  }
#undef K8_LDB
#undef K8_MM

  #pragma unroll
  for (int ns = 0; ns < 4; ++ns)
    #pragma unroll
    for (int rr = 0; rr < 4; ++rr) {
      int n = ns*16 + kg*4 + rr;
      float inv = inv_lds[n];
      #pragma unroll
      for (int j = 0; j < 2; ++j) {
        float val = acc[ns][j][rr] * inv;
        val = (val > 0.f) ? val : expm1f(val);    // elu
        g[((size_t)z*DD + n0 + n)*WW + oh*128 + w*32 + j*16 + ln] = val;
      }
    }
}

// ---------- K8b: row log_softmax over o(256) -> gaty bf16 ----------
__global__ __launch_bounds__(256) void k8_lsm(
    const float* __restrict__ g, u16* __restrict__ gatybf)
{
  int row = blockIdx.x*4 + (threadIdx.x >> 6);
  int lane = threadIdx.x & 63;
  const float* gr = g + (size_t)row*WW;
  float v0 = gr[lane], v1 = gr[lane+64], v2 = gr[lane+128], v3 = gr[lane+192];
  float mx = fmaxf(fmaxf(v0,v1), fmaxf(v2,v3));
  #pragma unroll
  for (int off = 32; off >= 1; off >>= 1) mx = fmaxf(mx, __shfl_xor(mx, off));
  float sm = expf(v0-mx) + expf(v1-mx) + expf(v2-mx) + expf(v3-mx);
  #pragma unroll
  for (int off = 32; off >= 1; off >>= 1) sm += __shfl_xor(sm, off);
  float lg = mx + logf(sm);
  u16* go = gatybf + (size_t)row*WW;
  go[lane]     = f2bf(v0 - lg);
  go[lane+64]  = f2bf(v1 - lg);
  go[lane+128] = f2bf(v2 - lg);
  go[lane+192] = f2bf(v3 - lg);
}

// ---------- K9: out = gaty^T @ pW^T + pb ----------
__global__ __launch_bounds__(256) void k9_proj(
    const u16* __restrict__ gatybf, const u16* __restrict__ pWbf, const float* __restrict__ pb,
    int zb, float* __restrict__ out0)
{
  __shared__ u16 gt[64*40];
  const int t0 = blockIdx.x*64, d0 = blockIdx.y*64, z = blockIdx.z;
  const int tid = threadIdx.x;
  const int w = tid >> 6, l = tid & 63, ln = l & 15, kg = l >> 4;
  const int el = tid >> 3, t8 = tid & 7;
  f32x4 acc[4];
  #pragma unroll
  for (int os=0;os<4;++os) acc[os] = (f32x4){0.f,0.f,0.f,0.f};
  for (int e0 = 0; e0 < DD; e0 += 32) {
    __syncthreads();
    BF8 g8;
    g8.v = *reinterpret_cast<const short8*>(gatybf + ((size_t)z*DD + e0 + el)*WW + t0 + t8*8);
    #pragma unroll
    for (int j = 0; j < 8; ++j) gt[(t8*8 + j)*40 + el] = g8.u[j];
    __syncthreads();
    short8 a = *reinterpret_cast<const short8*>(&gt[(w*16 + ln)*40 + kg*8]);
    #pragma unroll
    for (int os = 0; os < 4; ++os) {
      short8 b = *reinterpret_cast<const short8*>(pWbf + (size_t)(d0 + os*16 + ln)*DD + e0 + kg*8);
      acc[os] = __builtin_amdgcn_mfma_f32_16x16x32_bf16(a, b, acc[os], 0,0,0);
    }
  }
  #pragma unroll
  for (int os=0; os<4; ++os)
    #pragma unroll
    for (int rr=0; rr<4; ++rr) {
      int t = t0 + w*16 + kg*4 + rr;
      int d = d0 + os*16 + ln;
      out0[((size_t)(zb+z)*WW + t)*DD + d] = acc[os][rr] + pb[d];
    }
}

extern "C" void kernel_launch(void* const* d_in, const int* in_sizes, int n_in,
                              void* d_out, int out_size, void* d_ws, size_t ws_size,
                              hipStream_t stream)
{
  const float* x   = (const float*)d_in[0];
  const float* qW  = (const float*)d_in[1];
  const float* qb  = (const float*)d_in[2];
  const float* kW  = (const float*)d_in[3];
  const float* kb  = (const float*)d_in[4];
  const float* vW  = (const float*)d_in[5];
  const float* vb  = (const float*)d_in[6];
  const float* hW  = (const float*)d_in[7];
  const float* hb  = (const float*)d_in[8];
  const float* hai = (const float*)d_in[9];
  const float* haib= (const float*)d_in[10];
  const float* haj = (const float*)d_in[11];
  const float* hajb= (const float*)d_in[12];
  const float* oW  = (const float*)d_in[13];
  const float* ob  = (const float*)d_in[14];
  const float* oai = (const float*)d_in[15];
  const float* oaib= (const float*)d_in[16];
  const float* oaj = (const float*)d_in[17];
  const float* oajb= (const float*)d_in[18];
  const float* pW  = (const float*)d_in[19];
  const float* pb  = (const float*)d_in[20];

  float* out0 = (float*)d_out;                   // [B,W,D] f32
  float* adjo = out0 + (size_t)BB*WW*DD;         // [B,D,D] f32

  // static region (float offsets)
  float* ws      = (float*)d_ws;
  u16*   Wt      = (u16*)(ws + 0);           // 1,179,648 f
  u16*   hWbf    = (u16*)(ws + 1179648);     //    65,536 f
  u16*   oWbf    = (u16*)(ws + 1245184);     //    65,536 f
  u16*   pWbf    = (u16*)(ws + 1310720);     //   131,072 f
  float* ahat_i  = ws + 1441792;
  float* ahat_j  = ws + 1442816;
  float* oahat_i = ws + 1443840;
  float* oahat_j = ws + 1444352;
  float* cvec    = ws + 1444864;
  float* e1h     = ws + 1444880;             //    65,536 f (CB=32 max)
  float* e2h     = ws + 1510416;
  float* e1o     = ws + 1575952;             //    16,384 f
  float* e2o     = ws + 1592336;
  const size_t X0 = 1608720;                 // dynamic region start

  // per-CB dynamic: xpad 66,048 + vbf 65,536 + qbf 65,536 + kbf 65,536 + Whtbf 131,072 = 393,728 f
  int CB = 4;
  {
    const int cand[3] = {32, 16, 8};
    for (int i = 0; i < 3; ++i) {
      size_t need = (X0 + (size_t)cand[i]*393728) * 4;
      if (need <= ws_size) { CB = cand[i]; break; }
    }
  }

  u16* xpad   = (u16*)(ws + X0);                        // CB*66,048 f  ([z][258][512])
  u16* vbf    = (u16*)(ws + X0 + (size_t)CB*66048);     // CB*65,536 f
  u16* qbf    = (u16*)(ws + X0 + (size_t)CB*131584);    // CB*65,536 f
  u16* kbf    = (u16*)(ws + X0 + (size_t)CB*197120);    // CB*65,536 f
  u16* Whtbf  = (u16*)(ws + X0 + (size_t)CB*262656);    // CB*131,072 f
  // overlays (lifetimes: xpad dead after k1; vbf dead after k4; qbf,kbf dead after k2;
  // hcatbf dead after k7; Whtbf dead after k5)
  u16*   hcatbf = (u16*)(ws + X0);                      // over xpad+vbf
  float* g      = (float*)(ws + X0);                    // over hcatbf region (k8 phase)
  u16*   gatybf = (u16*)(ws + X0 + (size_t)CB*131584);  // over qbf
  u16*   Wh2tbf = (u16*)(ws + X0 + (size_t)CB*197120);  // over kbf

  kprep_w<<<dim3((3*DD*DD + 255)/256), 256, 0, stream>>>(qW, kW, vW, Wt);
  kcvt<<<dim3((NHEADS*NHID*WW + 255)/256), 256, 0, stream>>>(hW, hWbf, NHEADS*NHID*WW);
  kcvt<<<dim3((WW*DD + 255)/256), 256, 0, stream>>>(oW, oWbf, WW*DD);
  kcvt<<<dim3((DD*DD + 255)/256), 256, 0, stream>>>(pW, pWbf, DD*DD);
  kprep_a<<<dim3(13), 256, 0, stream>>>(hW, hai, haib, haj, hajb, hb,
                                        oW, oai, oaib, oaj, oajb, ob,
                                        ahat_i, ahat_j, oahat_i, oahat_j, cvec);

  for (int zb = 0; zb < BB; zb += CB) {
    int nrow8 = CB*258*64;
    kprep_x  <<<dim3((nrow8 + 255)/256), 256, 0, stream>>>(x, zb, nrow8, xpad);
    k1_mfma  <<<dim3(DD/64, WW/128, CB), 256, 0, stream>>>(xpad, Wt, qb, kb, vb, qbf, kbf, vbf);
    k2_adj   <<<dim3(DD/64, DD/64, CB), 256, 0, stream>>>(qbf, kbf, zb, adjo);
    k3_wh    <<<dim3(DD/64, NHID/64, CB*NHEADS), 256, 0, stream>>>(vbf, hWbf, hb, Whtbf);
    k4_eheads<<<dim3(CB*NHEADS*DD/4), 256, 0, stream>>>(vbf, ahat_i, ahat_j, cvec, e1h, e2h);
    k5_attn  <<<dim3(DD/64, CB*NHEADS), 256, 0, stream>>>(e1h, e2h, Whtbf, hcatbf);
    k6_wh2   <<<dim3(DD/64, WW/64, CB), 256, 0, stream>>>(hcatbf, oWbf, ob, Wh2tbf);
    k7_eout  <<<dim3(CB*DD/4), 256, 0, stream>>>(hcatbf, oahat_i, oahat_j, cvec, e1o, e2o);
    k8_pv    <<<dim3(DD/64, CB, 2), 256, 0, stream>>>(e1o, e2o, Wh2tbf, g);
    k8_lsm   <<<dim3(CB*128), 256, 0, stream>>>(g, gatybf);
    k9_proj  <<<dim3(WW/64, DD/64, CB), 256, 0, stream>>>(gatybf, pWbf, pb, zb, out0);
  }
}